// Round 1
// baseline (1512.896 us; speedup 1.0000x reference)
//
#include <hip/hip_runtime.h>
#include <math.h>

#define D_MODEL   1024
#define N_HEADS   16
#define H_DIM     64
#define SEQ       2048
#define BATCH     2
#define ROWS      (BATCH * SEQ)        // 4096
#define THREE_D   (3 * D_MODEL)       // 3072

// ---------------------------------------------------------------------------
// GEMM:  C[M,N] = A[M,K](row-major, lda) * B[N,K](row-major, ldb)^T + bias[N]
// grid = (N/128, M/128), 256 threads, 8x8 per-thread microtile.
// Requires M%128==0, N%128==0, K%16==0 (all shapes here comply).
// ---------------------------------------------------------------------------
__global__ __launch_bounds__(256)
void gemm_bt_f32(const float* __restrict__ A, int lda,
                 const float* __restrict__ B, int ldb,
                 const float* __restrict__ bias,
                 float* __restrict__ C, int ldc, int K)
{
    __shared__ float As[16][128];
    __shared__ float Bs[16][128];

    const int bm = blockIdx.y * 128;
    const int bn = blockIdx.x * 128;
    const int t  = threadIdx.x;
    const int tx = t & 15;
    const int ty = t >> 4;

    const int r  = t >> 2;   // 0..63 (staging row)
    const int c4 = t & 3;    // 0..3  (staging float4 column)

    const float* Ap = A + (size_t)(bm + r) * lda + (c4 << 2);
    const float* Bp = B + (size_t)(bn + r) * ldb + (c4 << 2);

    float acc[8][8];
#pragma unroll
    for (int i = 0; i < 8; ++i)
#pragma unroll
        for (int j = 0; j < 8; ++j) acc[i][j] = 0.f;

    for (int k0 = 0; k0 < K; k0 += 16) {
#pragma unroll
        for (int half = 0; half < 2; ++half) {
            const int row = r + (half << 6);
            float4 va = *reinterpret_cast<const float4*>(Ap + (size_t)(half << 6) * lda + k0);
            As[(c4 << 2) + 0][row] = va.x;
            As[(c4 << 2) + 1][row] = va.y;
            As[(c4 << 2) + 2][row] = va.z;
            As[(c4 << 2) + 3][row] = va.w;
            float4 vb = *reinterpret_cast<const float4*>(Bp + (size_t)(half << 6) * ldb + k0);
            Bs[(c4 << 2) + 0][row] = vb.x;
            Bs[(c4 << 2) + 1][row] = vb.y;
            Bs[(c4 << 2) + 2][row] = vb.z;
            Bs[(c4 << 2) + 3][row] = vb.w;
        }
        __syncthreads();
#pragma unroll
        for (int k = 0; k < 16; ++k) {
            float a[8], b[8];
            *reinterpret_cast<float4*>(&a[0]) = *reinterpret_cast<const float4*>(&As[k][ty * 8]);
            *reinterpret_cast<float4*>(&a[4]) = *reinterpret_cast<const float4*>(&As[k][ty * 8 + 4]);
            *reinterpret_cast<float4*>(&b[0]) = *reinterpret_cast<const float4*>(&Bs[k][tx * 8]);
            *reinterpret_cast<float4*>(&b[4]) = *reinterpret_cast<const float4*>(&Bs[k][tx * 8 + 4]);
#pragma unroll
            for (int i = 0; i < 8; ++i)
#pragma unroll
                for (int j = 0; j < 8; ++j)
                    acc[i][j] = fmaf(a[i], b[j], acc[i][j]);
        }
        __syncthreads();
    }

#pragma unroll
    for (int i = 0; i < 8; ++i) {
        const size_t row = (size_t)(bm + ty * 8 + i);
#pragma unroll
        for (int jj = 0; jj < 2; ++jj) {
            const int col = bn + tx * 8 + (jj << 2);
            float4 bb = *reinterpret_cast<const float4*>(&bias[col]);
            float4 o;
            o.x = acc[i][(jj << 2) + 0] + bb.x;
            o.y = acc[i][(jj << 2) + 1] + bb.y;
            o.z = acc[i][(jj << 2) + 2] + bb.z;
            o.w = acc[i][(jj << 2) + 3] + bb.w;
            *reinterpret_cast<float4*>(&C[row * ldc + col]) = o;
        }
    }
}

// ---------------------------------------------------------------------------
// RoPE cos/sin table: SEQ x 32 entries of (cos, sin), computed in fp64 once.
// ---------------------------------------------------------------------------
__global__ void rope_table(float* __restrict__ tab)
{
    const int idx = blockIdx.x * 256 + threadIdx.x;   // 0 .. SEQ*32-1
    const int s = idx >> 5;
    const int i = idx & 31;
    const double inv = pow(10000.0, -(double)(2 * i) / 64.0);
    const double f = (double)s * inv;
    tab[idx * 2 + 0] = (float)cos(f);
    tab[idx * 2 + 1] = (float)sin(f);
}

// ---------------------------------------------------------------------------
// RoPE applied in place on combined[:, 0:2048) (q and k thirds).
// One thread per rotation pair. 2 * ROWS * 16 * 32 = 2^22 threads.
// ---------------------------------------------------------------------------
__global__ void rope_apply(float* __restrict__ comb, const float* __restrict__ tab)
{
    const int idx = blockIdx.x * 256 + threadIdx.x;
    const int i     = idx & 31;
    const int h     = (idx >> 5) & 15;
    const int row   = (idx >> 9) & (ROWS - 1);
    const int which = idx >> 21;                 // 0 = q third, 1 = k third
    const int s     = row & (SEQ - 1);

    const float c  = tab[(s * 32 + i) * 2 + 0];
    const float sn = tab[(s * 32 + i) * 2 + 1];

    float* base = comb + (size_t)row * THREE_D + which * D_MODEL + h * H_DIM;
    const float t1 = base[i];
    const float t2 = base[i + 32];
    base[i]      = t1 * c - t2 * sn;
    base[i + 32] = t2 * c + t1 * sn;
}

// ---------------------------------------------------------------------------
// Flash-style attention, fp32 vector.
// grid = (SEQ/64, BATCH*N_HEADS), 256 threads.
// Each block: 64 q-rows of one (b,h). Iterates 64-key tiles with online
// softmax. Per-thread 4x4 microtiles; P staged through padded LDS.
// ---------------------------------------------------------------------------
__global__ __launch_bounds__(256)
void attn_f32(const float* __restrict__ Qg, const float* __restrict__ Kg,
              const float* __restrict__ Vg, float* __restrict__ ctx)
{
    __shared__ float QsT[64][64];   // [d][qi]
    __shared__ float KVs[64][64];   // phase 1: KsT[d][kj]; phase 2: Vs[k][d]
    __shared__ float Ps[64][68];    // [qi][k], padded (+4) -> 2-way reads

    const int bh = blockIdx.y;
    const int b  = bh >> 4;          // / N_HEADS
    const int h  = bh & 15;
    const int q0 = blockIdx.x * 64;
    const size_t rowBase = (size_t)b * SEQ;
    const int hOff = h * H_DIM;

    const int t  = threadIdx.x;
    const int tx = t & 15;
    const int ty = t >> 4;

    // ---- stage Q transposed: QsT[d][qi]
    {
        const int qi = t & 63;
        const int c0 = t >> 6;       // 0..3
#pragma unroll
        for (int it = 0; it < 4; ++it) {
            const int cc = c0 + it * 4;   // 0..15
            float4 v = *reinterpret_cast<const float4*>(
                &Qg[(rowBase + q0 + qi) * D_MODEL + hOff + cc * 4]);
            QsT[cc * 4 + 0][qi] = v.x;
            QsT[cc * 4 + 1][qi] = v.y;
            QsT[cc * 4 + 2][qi] = v.z;
            QsT[cc * 4 + 3][qi] = v.w;
        }
    }

    float m[4], l[4], acc[4][4];
#pragma unroll
    for (int i = 0; i < 4; ++i) {
        m[i] = -1e30f;
        l[i] = 0.f;
#pragma unroll
        for (int j = 0; j < 4; ++j) acc[i][j] = 0.f;
    }

    for (int k0 = 0; k0 < SEQ; k0 += 64) {
        __syncthreads();   // previous PV reads done (and Q staged, iter 0)
        // ---- stage K transposed: KsT[d][kj]
        {
            const int kj = t & 63;
            const int c0 = t >> 6;
#pragma unroll
            for (int it = 0; it < 4; ++it) {
                const int cc = c0 + it * 4;
                float4 v = *reinterpret_cast<const float4*>(
                    &Kg[(rowBase + k0 + kj) * D_MODEL + hOff + cc * 4]);
                KVs[cc * 4 + 0][kj] = v.x;
                KVs[cc * 4 + 1][kj] = v.y;
                KVs[cc * 4 + 2][kj] = v.z;
                KVs[cc * 4 + 3][kj] = v.w;
            }
        }
        __syncthreads();

        // ---- scores: s[i][j] = q(ty*4+i) . k(tx*4+j)
        float s[4][4];
#pragma unroll
        for (int i = 0; i < 4; ++i)
#pragma unroll
            for (int j = 0; j < 4; ++j) s[i][j] = 0.f;

#pragma unroll 8
        for (int d = 0; d < 64; ++d) {
            float4 qv = *reinterpret_cast<const float4*>(&QsT[d][ty * 4]);
            float4 kv = *reinterpret_cast<const float4*>(&KVs[d][tx * 4]);
            const float qa[4] = {qv.x, qv.y, qv.z, qv.w};
            const float ka[4] = {kv.x, kv.y, kv.z, kv.w};
#pragma unroll
            for (int i = 0; i < 4; ++i)
#pragma unroll
                for (int j = 0; j < 4; ++j)
                    s[i][j] = fmaf(qa[i], ka[j], s[i][j]);
        }

        // ---- online softmax (row = ty*4+i spans the 16 tx lanes)
#pragma unroll
        for (int i = 0; i < 4; ++i) {
            float tm = -1e30f;
#pragma unroll
            for (int j = 0; j < 4; ++j) {
                s[i][j] *= 0.125f;               // 1/sqrt(64)
                tm = fmaxf(tm, s[i][j]);
            }
            tm = fmaxf(tm, __shfl_xor(tm, 1));
            tm = fmaxf(tm, __shfl_xor(tm, 2));
            tm = fmaxf(tm, __shfl_xor(tm, 4));
            tm = fmaxf(tm, __shfl_xor(tm, 8));

            const float mn = fmaxf(m[i], tm);
            const float sc = expf(m[i] - mn);
            float rs = 0.f;
#pragma unroll
            for (int j = 0; j < 4; ++j) {
                const float p = expf(s[i][j] - mn);
                s[i][j] = p;
                rs += p;
            }
            rs += __shfl_xor(rs, 1);
            rs += __shfl_xor(rs, 2);
            rs += __shfl_xor(rs, 4);
            rs += __shfl_xor(rs, 8);

            l[i] = l[i] * sc + rs;
            m[i] = mn;
#pragma unroll
            for (int j = 0; j < 4; ++j) acc[i][j] *= sc;

            float4 pv = {s[i][0], s[i][1], s[i][2], s[i][3]};
            *reinterpret_cast<float4*>(&Ps[ty * 4 + i][tx * 4]) = pv;
        }

        __syncthreads();   // Ps complete, K reads complete
        // ---- stage V row-major into same buffer: Vs[k][d]
        {
            const int c4 = t & 15;
            const int r0 = t >> 4;
#pragma unroll
            for (int it = 0; it < 4; ++it) {
                const int rr = r0 + it * 16;
                float4 v = *reinterpret_cast<const float4*>(
                    &Vg[(rowBase + k0 + rr) * D_MODEL + hOff + c4 * 4]);
                *reinterpret_cast<float4*>(&KVs[rr][c4 * 4]) = v;
            }
        }
        __syncthreads();

        // ---- PV: acc[i][j] += sum_k Ps[qi][k] * Vs[k][dj]
#pragma unroll 8
        for (int k = 0; k < 64; ++k) {
            float4 vv = *reinterpret_cast<const float4*>(&KVs[k][tx * 4]);
            const float vb[4] = {vv.x, vv.y, vv.z, vv.w};
#pragma unroll
            for (int i = 0; i < 4; ++i) {
                const float p = Ps[ty * 4 + i][k];
#pragma unroll
                for (int j = 0; j < 4; ++j)
                    acc[i][j] = fmaf(p, vb[j], acc[i][j]);
            }
        }
    }

    // ---- epilogue: ctx = acc / l
#pragma unroll
    for (int i = 0; i < 4; ++i) {
        const float inv = 1.f / l[i];
        float4 o;
        o.x = acc[i][0] * inv;
        o.y = acc[i][1] * inv;
        o.z = acc[i][2] * inv;
        o.w = acc[i][3] * inv;
        *reinterpret_cast<float4*>(
            &ctx[(rowBase + q0 + ty * 4 + i) * D_MODEL + hOff + tx * 4]) = o;
    }
}

// ---------------------------------------------------------------------------
extern "C" void kernel_launch(void* const* d_in, const int* in_sizes, int n_in,
                              void* d_out, int out_size, void* d_ws, size_t ws_size,
                              hipStream_t stream)
{
    const float* x    = (const float*)d_in[0];
    const float* Win  = (const float*)d_in[1];   // (3072, 1024)
    const float* bin  = (const float*)d_in[2];   // (3072,)
    const float* Wout = (const float*)d_in[3];   // (1024, 1024)
    const float* bout = (const float*)d_in[4];   // (1024,)
    float* out = (float*)d_out;

    float* combined = (float*)d_ws;                                  // ROWS x 3072
    float* qbuf = combined + (size_t)ROWS * THREE_D;                 // ROWS x 1024
    float* kbuf = qbuf + (size_t)ROWS * D_MODEL;
    float* vbuf = kbuf + (size_t)ROWS * D_MODEL;
    float* tab  = vbuf + (size_t)ROWS * D_MODEL;                     // SEQ*32*2
    float* ctx  = combined;                                          // reuse

    const dim3 blk(256);

    // trig table (fp64 accuracy, tiny)
    rope_table<<<dim3(SEQ * 32 / 256), blk, 0, stream>>>(tab);

    // GEMM1: combined = x @ Win^T + bin   (M=4096, N=3072, K=1024)
    gemm_bt_f32<<<dim3(THREE_D / 128, ROWS / 128), blk, 0, stream>>>(
        x, D_MODEL, Win, D_MODEL, bin, combined, THREE_D, D_MODEL);

    // RoPE in place on q/k thirds of combined
    rope_apply<<<dim3((2 * ROWS * N_HEADS * 32) / 256), blk, 0, stream>>>(combined, tab);

    // GEMM2: q = rope(q0) @ Wq^T + bq ; k = rope(k0) @ Wk^T + bk ; v = v0 @ Wv^T + bv
    gemm_bt_f32<<<dim3(D_MODEL / 128, ROWS / 128), blk, 0, stream>>>(
        combined + 0,            THREE_D, Win + 0,                         D_MODEL,
        bin + 0,        qbuf, D_MODEL, D_MODEL);
    gemm_bt_f32<<<dim3(D_MODEL / 128, ROWS / 128), blk, 0, stream>>>(
        combined + D_MODEL,      THREE_D, Win + (size_t)D_MODEL * D_MODEL, D_MODEL,
        bin + D_MODEL,  kbuf, D_MODEL, D_MODEL);
    gemm_bt_f32<<<dim3(D_MODEL / 128, ROWS / 128), blk, 0, stream>>>(
        combined + 2 * D_MODEL,  THREE_D, Win + (size_t)2 * D_MODEL * D_MODEL, D_MODEL,
        bin + 2 * D_MODEL, vbuf, D_MODEL, D_MODEL);

    // attention -> ctx (reuses combined storage)
    attn_f32<<<dim3(SEQ / 64, BATCH * N_HEADS), blk, 0, stream>>>(qbuf, kbuf, vbuf, ctx);

    // GEMM3: out = ctx @ Wout^T + bout
    gemm_bt_f32<<<dim3(D_MODEL / 128, ROWS / 128), blk, 0, stream>>>(
        ctx, D_MODEL, Wout, D_MODEL, bout, out, D_MODEL, D_MODEL);
}

// Round 2
// 1437.221 us; speedup vs baseline: 1.0527x; 1.0527x over previous
//
#include <hip/hip_runtime.h>
#include <math.h>

#define D_MODEL   1024
#define N_HEADS   16
#define H_DIM     64
#define SEQ       2048
#define BATCH     2
#define ROWS      (BATCH * SEQ)        // 4096
#define THREE_D   (3 * D_MODEL)       // 3072

// q pre-scale: 1/sqrt(64) * log2(e)  -> softmax in exp2 domain
#define QK_SCALE  (0.125f * 1.44269504088896340736f)

__device__ __forceinline__ void async_copy16(const float* g, float* l)
{
    __builtin_amdgcn_global_load_lds(
        (const __attribute__((address_space(1))) void*)g,
        (__attribute__((address_space(3))) void*)l,
        16, 0, 0);
}

// ---------------------------------------------------------------------------
// GEMM:  C[M,N] = A[M,K] * B[N,K]^T + bias[N]     (both row-major, K contig)
// 128x128 tile, BK=32, double-buffered LDS staged via global_load_lds,
// one barrier per k-step. XOR-swizzled kgroups keyed on (row>>3)&7.
// Segmented launch: seg = blockIdx.x / nbx selects A/B/bias/C offsets
// (used to fuse the q/k/v projections into one dispatch).
// ---------------------------------------------------------------------------
__global__ __launch_bounds__(256)
void gemm_bt_db(const float* __restrict__ A, int lda,
                const float* __restrict__ B, int ldb,
                const float* __restrict__ bias,
                float* __restrict__ C, int ldc, int K,
                int nbx, size_t segA, size_t segB, int segBias, size_t segC)
{
    __shared__ __align__(16) float As[2][128 * 32];
    __shared__ __align__(16) float Bs[2][128 * 32];

    const int seg = blockIdx.x / nbx;
    const int bxs = blockIdx.x - seg * nbx;
    const int bm  = blockIdx.y * 128;
    const int bn  = bxs * 128;
    A    += (size_t)seg * segA;
    B    += (size_t)seg * segB;
    bias += seg * segBias;
    C    += (size_t)seg * segC;

    const int t    = threadIdx.x;
    const int tx   = t & 15;
    const int ty   = t >> 4;
    const int wid  = t >> 6;
    const int lane = t & 63;
    const int lrow = lane >> 3;   // 0..7 : row within 8-row stripe
    const int gs   = lane & 7;    // stored kgroup slot

    // stage one 128x32 tile of A and B into buffer `buf` at k-offset k0.
    // LDS dest is wave-uniform (r0*32 floats); HW scatters lane*16B.
    // Global source column is pre-swizzled so that stored slot gs holds
    // logical kgroup gl = gs ^ ((row>>3)&7).
    auto stage = [&](int buf, int k0) {
#pragma unroll
        for (int q = 0; q < 4; ++q) {
            const int r0  = (wid * 4 + q) * 8;
            const int row = r0 + lrow;
            const int gl  = gs ^ ((row >> 3) & 7);
            async_copy16(A + (size_t)(bm + row) * lda + k0 + (gl << 2),
                         &As[buf][r0 * 32]);
            async_copy16(B + (size_t)(bn + row) * ldb + k0 + (gl << 2),
                         &Bs[buf][r0 * 32]);
        }
    };

    float acc[8][8];
#pragma unroll
    for (int i = 0; i < 8; ++i)
#pragma unroll
        for (int j = 0; j < 8; ++j) acc[i][j] = 0.f;

    const int NT = K >> 5;
    stage(0, 0);

    for (int it = 0; it < NT; ++it) {
        __syncthreads();               // drains vmcnt: tile `it` landed
        if (it + 1 < NT)
            stage((it + 1) & 1, (it + 1) << 5);

        const float* as = As[it & 1];
        const float* bs = Bs[it & 1];
#pragma unroll
        for (int g = 0; g < 8; ++g) {
            float4 a4[8], b4[8];
#pragma unroll
            for (int i = 0; i < 8; ++i)
                a4[i] = *reinterpret_cast<const float4*>(
                    as + (ty * 8 + i) * 32 + (((g ^ ((ty * 8 + i) >> 3)) & 7) << 2));
#pragma unroll
            for (int j = 0; j < 8; ++j)
                b4[j] = *reinterpret_cast<const float4*>(
                    bs + (tx * 8 + j) * 32 + (((g ^ ((tx * 8 + j) >> 3)) & 7) << 2));
#pragma unroll
            for (int kk = 0; kk < 4; ++kk) {
#pragma unroll
                for (int i = 0; i < 8; ++i) {
                    const float av = reinterpret_cast<const float*>(&a4[i])[kk];
#pragma unroll
                    for (int j = 0; j < 8; ++j)
                        acc[i][j] = fmaf(av,
                            reinterpret_cast<const float*>(&b4[j])[kk], acc[i][j]);
                }
            }
        }
    }

#pragma unroll
    for (int i = 0; i < 8; ++i) {
        const size_t row = (size_t)(bm + ty * 8 + i);
#pragma unroll
        for (int jj = 0; jj < 2; ++jj) {
            const int col = bn + tx * 8 + (jj << 2);
            float4 bb = *reinterpret_cast<const float4*>(&bias[col]);
            float4 o;
            o.x = acc[i][(jj << 2) + 0] + bb.x;
            o.y = acc[i][(jj << 2) + 1] + bb.y;
            o.z = acc[i][(jj << 2) + 2] + bb.z;
            o.w = acc[i][(jj << 2) + 3] + bb.w;
            *reinterpret_cast<float4*>(&C[row * ldc + col]) = o;
        }
    }
}

// ---------------------------------------------------------------------------
// RoPE cos/sin table: SEQ x 32 entries of (cos, sin), computed in fp64 once.
// ---------------------------------------------------------------------------
__global__ void rope_table(float* __restrict__ tab)
{
    const int idx = blockIdx.x * 256 + threadIdx.x;   // 0 .. SEQ*32-1
    const int s = idx >> 5;
    const int i = idx & 31;
    const double inv = pow(10000.0, -(double)(2 * i) / 64.0);
    const double f = (double)s * inv;
    tab[idx * 2 + 0] = (float)cos(f);
    tab[idx * 2 + 1] = (float)sin(f);
}

// ---------------------------------------------------------------------------
// RoPE applied in place on combined q/k thirds.
// ---------------------------------------------------------------------------
__global__ void rope_apply(float* __restrict__ comb, const float* __restrict__ tab)
{
    const int idx = blockIdx.x * 256 + threadIdx.x;
    const int i     = idx & 31;
    const int h     = (idx >> 5) & 15;
    const int row   = (idx >> 9) & (ROWS - 1);
    const int which = idx >> 21;                 // 0 = q third, 1 = k third
    const int s     = row & (SEQ - 1);

    const float c  = tab[(s * 32 + i) * 2 + 0];
    const float sn = tab[(s * 32 + i) * 2 + 1];

    float* base = comb + (size_t)row * THREE_D + which * D_MODEL + h * H_DIM;
    const float t1 = base[i];
    const float t2 = base[i + 32];
    base[i]      = t1 * c - t2 * sn;
    base[i + 32] = t2 * c + t1 * sn;
}

// ---------------------------------------------------------------------------
// Flash-style attention, fp32 vector, exp2-domain softmax, defer-max (THR=8).
// grid = (SEQ/64, BATCH*N_HEADS), 256 threads.
// ---------------------------------------------------------------------------
__global__ __launch_bounds__(256)
void attn_f32(const float* __restrict__ Qg, const float* __restrict__ Kg,
              const float* __restrict__ Vg, float* __restrict__ ctx)
{
    __shared__ __align__(16) float QsT[64][64];   // [d][qi], pre-scaled
    __shared__ __align__(16) float KVs[64][64];   // phase 1: KsT[d][kj]; phase 2: Vs[k][d]
    __shared__ __align__(16) float Ps[64][68];    // [qi][k], padded

    const int bh = blockIdx.y;
    const int b  = bh >> 4;
    const int h  = bh & 15;
    const int q0 = blockIdx.x * 64;
    const size_t rowBase = (size_t)b * SEQ;
    const int hOff = h * H_DIM;

    const int t  = threadIdx.x;
    const int tx = t & 15;
    const int ty = t >> 4;

    // ---- stage Q transposed + pre-scaled: QsT[d][qi]
    {
        const int qi = t & 63;
        const int c0 = t >> 6;
#pragma unroll
        for (int it = 0; it < 4; ++it) {
            const int cc = c0 + it * 4;
            float4 v = *reinterpret_cast<const float4*>(
                &Qg[(rowBase + q0 + qi) * D_MODEL + hOff + cc * 4]);
            QsT[cc * 4 + 0][qi] = v.x * QK_SCALE;
            QsT[cc * 4 + 1][qi] = v.y * QK_SCALE;
            QsT[cc * 4 + 2][qi] = v.z * QK_SCALE;
            QsT[cc * 4 + 3][qi] = v.w * QK_SCALE;
        }
    }

    float m[4], l[4], acc[4][4];
#pragma unroll
    for (int i = 0; i < 4; ++i) {
        m[i] = -1e30f;
        l[i] = 0.f;
#pragma unroll
        for (int j = 0; j < 4; ++j) acc[i][j] = 0.f;
    }

    for (int k0 = 0; k0 < SEQ; k0 += 64) {
        __syncthreads();
        // ---- stage K transposed: KsT[d][kj]
        {
            const int kj = t & 63;
            const int c0 = t >> 6;
#pragma unroll
            for (int it = 0; it < 4; ++it) {
                const int cc = c0 + it * 4;
                float4 v = *reinterpret_cast<const float4*>(
                    &Kg[(rowBase + k0 + kj) * D_MODEL + hOff + cc * 4]);
                KVs[cc * 4 + 0][kj] = v.x;
                KVs[cc * 4 + 1][kj] = v.y;
                KVs[cc * 4 + 2][kj] = v.z;
                KVs[cc * 4 + 3][kj] = v.w;
            }
        }
        __syncthreads();

        // ---- scores (already in log2 domain via QK_SCALE)
        float s[4][4];
#pragma unroll
        for (int i = 0; i < 4; ++i)
#pragma unroll
            for (int j = 0; j < 4; ++j) s[i][j] = 0.f;

#pragma unroll 8
        for (int d = 0; d < 64; ++d) {
            float4 qv = *reinterpret_cast<const float4*>(&QsT[d][ty * 4]);
            float4 kv = *reinterpret_cast<const float4*>(&KVs[d][tx * 4]);
            const float qa[4] = {qv.x, qv.y, qv.z, qv.w};
            const float ka[4] = {kv.x, kv.y, kv.z, kv.w};
#pragma unroll
            for (int i = 0; i < 4; ++i)
#pragma unroll
                for (int j = 0; j < 4; ++j)
                    s[i][j] = fmaf(qa[i], ka[j], s[i][j]);
        }

        // ---- online softmax, exp2 domain, defer-max THR=8
#pragma unroll
        for (int i = 0; i < 4; ++i) {
            float tm = fmaxf(fmaxf(s[i][0], s[i][1]), fmaxf(s[i][2], s[i][3]));
            tm = fmaxf(tm, __shfl_xor(tm, 1));
            tm = fmaxf(tm, __shfl_xor(tm, 2));
            tm = fmaxf(tm, __shfl_xor(tm, 4));
            tm = fmaxf(tm, __shfl_xor(tm, 8));

            if (tm > m[i] + 8.0f) {                      // rescale only when needed
                const float sc = __builtin_amdgcn_exp2f(m[i] - tm);
                l[i] *= sc;
#pragma unroll
                for (int j = 0; j < 4; ++j) acc[i][j] *= sc;
                m[i] = tm;
            }

            float rs = 0.f;
#pragma unroll
            for (int j = 0; j < 4; ++j) {
                const float p = __builtin_amdgcn_exp2f(s[i][j] - m[i]);
                s[i][j] = p;
                rs += p;
            }
            rs += __shfl_xor(rs, 1);
            rs += __shfl_xor(rs, 2);
            rs += __shfl_xor(rs, 4);
            rs += __shfl_xor(rs, 8);
            l[i] += rs;

            float4 pv = {s[i][0], s[i][1], s[i][2], s[i][3]};
            *reinterpret_cast<float4*>(&Ps[ty * 4 + i][tx * 4]) = pv;
        }

        __syncthreads();
        // ---- stage V row-major into same buffer: Vs[k][d]
        {
            const int c4 = t & 15;
            const int r0 = t >> 4;
#pragma unroll
            for (int it = 0; it < 4; ++it) {
                const int rr = r0 + it * 16;
                float4 v = *reinterpret_cast<const float4*>(
                    &Vg[(rowBase + k0 + rr) * D_MODEL + hOff + c4 * 4]);
                *reinterpret_cast<float4*>(&KVs[rr][c4 * 4]) = v;
            }
        }
        __syncthreads();

        // ---- PV: float4 reads of Ps over k (contiguous) and V rows
#pragma unroll
        for (int kk = 0; kk < 64; kk += 4) {
            float4 p4[4], v4[4];
#pragma unroll
            for (int i = 0; i < 4; ++i)
                p4[i] = *reinterpret_cast<const float4*>(&Ps[ty * 4 + i][kk]);
#pragma unroll
            for (int r = 0; r < 4; ++r)
                v4[r] = *reinterpret_cast<const float4*>(&KVs[kk + r][tx * 4]);
#pragma unroll
            for (int i = 0; i < 4; ++i) {
                const float* pp = reinterpret_cast<const float*>(&p4[i]);
#pragma unroll
                for (int r = 0; r < 4; ++r) {
                    const float p = pp[r];
                    const float* vv = reinterpret_cast<const float*>(&v4[r]);
                    acc[i][0] = fmaf(p, vv[0], acc[i][0]);
                    acc[i][1] = fmaf(p, vv[1], acc[i][1]);
                    acc[i][2] = fmaf(p, vv[2], acc[i][2]);
                    acc[i][3] = fmaf(p, vv[3], acc[i][3]);
                }
            }
        }
    }

    // ---- epilogue
#pragma unroll
    for (int i = 0; i < 4; ++i) {
        const float inv = 1.f / l[i];
        float4 o;
        o.x = acc[i][0] * inv;
        o.y = acc[i][1] * inv;
        o.z = acc[i][2] * inv;
        o.w = acc[i][3] * inv;
        *reinterpret_cast<float4*>(
            &ctx[(rowBase + q0 + ty * 4 + i) * D_MODEL + hOff + tx * 4]) = o;
    }
}

// ---------------------------------------------------------------------------
extern "C" void kernel_launch(void* const* d_in, const int* in_sizes, int n_in,
                              void* d_out, int out_size, void* d_ws, size_t ws_size,
                              hipStream_t stream)
{
    const float* x    = (const float*)d_in[0];
    const float* Win  = (const float*)d_in[1];   // (3072, 1024)
    const float* bin  = (const float*)d_in[2];   // (3072,)
    const float* Wout = (const float*)d_in[3];   // (1024, 1024)
    const float* bout = (const float*)d_in[4];   // (1024,)
    float* out = (float*)d_out;

    float* combined = (float*)d_ws;                                  // ROWS x 3072
    float* qkv  = combined + (size_t)ROWS * THREE_D;                 // 3 x ROWS x 1024
    float* qbuf = qkv;
    float* kbuf = qkv + (size_t)ROWS * D_MODEL;
    float* vbuf = kbuf + (size_t)ROWS * D_MODEL;
    float* tab  = vbuf + (size_t)ROWS * D_MODEL;                     // SEQ*32*2
    float* ctx  = combined;                                          // reuse

    const dim3 blk(256);

    rope_table<<<dim3(SEQ * 32 / 256), blk, 0, stream>>>(tab);

    // GEMM1: combined = x @ Win^T + bin   (M=4096, N=3072, K=1024)
    gemm_bt_db<<<dim3(24, 32), blk, 0, stream>>>(
        x, D_MODEL, Win, D_MODEL, bin, combined, THREE_D, D_MODEL,
        24, (size_t)0, (size_t)0, 0, (size_t)0);

    // RoPE in place on q/k thirds of combined
    rope_apply<<<dim3((2 * ROWS * N_HEADS * 32) / 256), blk, 0, stream>>>(combined, tab);

    // fused q/k/v second projection: seg = blockIdx.x/8 selects the third
    gemm_bt_db<<<dim3(24, 32), blk, 0, stream>>>(
        combined, THREE_D, Win, D_MODEL, bin, qkv, D_MODEL, D_MODEL,
        8, (size_t)D_MODEL, (size_t)D_MODEL * D_MODEL, D_MODEL,
        (size_t)ROWS * D_MODEL);

    // attention -> ctx (reuses combined storage)
    attn_f32<<<dim3(SEQ / 64, BATCH * N_HEADS), blk, 0, stream>>>(qbuf, kbuf, vbuf, ctx);

    // GEMM3: out = ctx @ Wout^T + bout
    gemm_bt_db<<<dim3(8, 32), blk, 0, stream>>>(
        ctx, D_MODEL, Wout, D_MODEL, bout, out, D_MODEL, D_MODEL,
        8, (size_t)0, (size_t)0, 0, (size_t)0);
}

// Round 3
// 903.637 us; speedup vs baseline: 1.6742x; 1.5905x over previous
//
#include <hip/hip_runtime.h>
#include <math.h>

#define D_MODEL   1024
#define N_HEADS   16
#define H_DIM     64
#define SEQ       2048
#define BATCH     2
#define ROWS      (BATCH * SEQ)        // 4096
#define THREE_D   (3 * D_MODEL)       // 3072

// q pre-scale: 1/sqrt(64) * log2(e)  -> softmax in exp2 domain
#define QK_SCALE  (0.125f * 1.44269504088896340736f)

typedef __attribute__((ext_vector_type(8))) short short8v;   // 8 bf16
typedef __attribute__((ext_vector_type(4))) float f32x4;

__device__ __forceinline__ void async_copy16(const float* g, float* l)
{
    __builtin_amdgcn_global_load_lds(
        (const __attribute__((address_space(1))) void*)g,
        (__attribute__((address_space(3))) void*)l,
        16, 0, 0);
}

// split fp32 -> 3 bf16 planes (truncation; residuals <=2^-8, 2^-16)
#define SPL(x, j)                                                          \
    {                                                                      \
        const float x_ = (x);                                              \
        const unsigned u1_ = __float_as_uint(x_);                          \
        const float r1_ = x_ - __uint_as_float(u1_ & 0xFFFF0000u);         \
        const unsigned u2_ = __float_as_uint(r1_);                         \
        const float r2_ = r1_ - __uint_as_float(u2_ & 0xFFFF0000u);        \
        h1[j] = (short)(u1_ >> 16);                                        \
        h2[j] = (short)(u2_ >> 16);                                        \
        h3[j] = (short)(__float_as_uint(r2_) >> 16);                       \
    }

// ---------------------------------------------------------------------------
// GEMM:  C[M,N] = A[M,K] * B[N,K]^T + bias[N]   via bf16x3-split MFMA.
// 128x128 tile, BK=32, fp32 LDS double-buffer staged with global_load_lds,
// XOR swizzle keyed on (row&7) so 16-row fragment reads are 2-way (free).
// 4 waves in 2x2; each wave: 64x64 = 4x4 subtiles of 16x16, K=32 per step.
// 6 MFMA per subtile pair-plane combo -> ~2^-22 relative product error.
// ---------------------------------------------------------------------------
__global__ __launch_bounds__(256, 2)
void gemm_bt_mfma(const float* __restrict__ A, int lda,
                  const float* __restrict__ B, int ldb,
                  const float* __restrict__ bias,
                  float* __restrict__ C, int ldc, int K,
                  int nbx, size_t segA, size_t segB, int segBias, size_t segC)
{
    __shared__ __align__(16) float As[2][128 * 32];
    __shared__ __align__(16) float Bs[2][128 * 32];

    const int seg = blockIdx.x / nbx;
    const int bxs = blockIdx.x - seg * nbx;
    const int bm  = blockIdx.y * 128;
    const int bn  = bxs * 128;
    A    += (size_t)seg * segA;
    B    += (size_t)seg * segB;
    bias += seg * segBias;
    C    += (size_t)seg * segC;

    const int t    = threadIdx.x;
    const int wid  = t >> 6;
    const int lane = t & 63;
    const int wr   = wid >> 1;      // wave row (0..1)
    const int wc   = wid & 1;       // wave col (0..1)
    const int cl   = lane & 15;     // fragment row/col within 16
    const int kq   = lane >> 4;     // k-octet index (0..3)
    const int lrow = lane >> 3;     // staging row within 8-stripe
    const int gs   = lane & 7;      // staging stored slot

    // stage one 128x32 fp32 tile of A and B into buffer `buf` at k0.
    // stored slot s of row r holds logical kgroup (s ^ (r&7)); achieved by
    // pre-swizzling the per-lane GLOBAL source (LDS dest stays linear).
    auto stage = [&](int buf, int k0) {
        const int gl = gs ^ lrow;                      // (row&7)==lrow
#pragma unroll
        for (int q = 0; q < 4; ++q) {
            const int r0  = (wid * 4 + q) * 8;
            const int row = r0 + lrow;
            async_copy16(A + (size_t)(bm + row) * lda + k0 + (gl << 2),
                         &As[buf][r0 * 32]);
            async_copy16(B + (size_t)(bn + row) * ldb + k0 + (gl << 2),
                         &Bs[buf][r0 * 32]);
        }
    };

    f32x4 acc[4][4];
#pragma unroll
    for (int m = 0; m < 4; ++m)
#pragma unroll
        for (int n = 0; n < 4; ++n) acc[m][n] = (f32x4)(0.f);

    const int NT = K >> 5;
    stage(0, 0);

    for (int it = 0; it < NT; ++it) {
        __syncthreads();               // tile `it` landed (vmcnt drained)
        if (it + 1 < NT)
            stage((it + 1) & 1, (it + 1) << 5);

        const float* as = As[it & 1];
        const float* bs = Bs[it & 1];

        short8v A1[4], A2[4], A3[4], B1[4], B2[4], B3[4];
#pragma unroll
        for (int m = 0; m < 4; ++m) {
            const int r  = wr * 64 + m * 16 + cl;
            const int s1 = (2 * kq) ^ (r & 7);
            const float4 lo = *reinterpret_cast<const float4*>(as + r * 32 + (s1 << 2));
            const float4 hi = *reinterpret_cast<const float4*>(as + r * 32 + ((s1 ^ 1) << 2));
            short8v h1, h2, h3;
            SPL(lo.x, 0) SPL(lo.y, 1) SPL(lo.z, 2) SPL(lo.w, 3)
            SPL(hi.x, 4) SPL(hi.y, 5) SPL(hi.z, 6) SPL(hi.w, 7)
            A1[m] = h1; A2[m] = h2; A3[m] = h3;
        }
#pragma unroll
        for (int n = 0; n < 4; ++n) {
            const int r  = wc * 64 + n * 16 + cl;
            const int s1 = (2 * kq) ^ (r & 7);
            const float4 lo = *reinterpret_cast<const float4*>(bs + r * 32 + (s1 << 2));
            const float4 hi = *reinterpret_cast<const float4*>(bs + r * 32 + ((s1 ^ 1) << 2));
            short8v h1, h2, h3;
            SPL(lo.x, 0) SPL(lo.y, 1) SPL(lo.z, 2) SPL(lo.w, 3)
            SPL(hi.x, 4) SPL(hi.y, 5) SPL(hi.z, 6) SPL(hi.w, 7)
            B1[n] = h1; B2[n] = h2; B3[n] = h3;
        }

#pragma unroll
        for (int m = 0; m < 4; ++m)
#pragma unroll
            for (int n = 0; n < 4; ++n) {
                f32x4 c = acc[m][n];
                c = __builtin_amdgcn_mfma_f32_16x16x32_bf16(A1[m], B1[n], c, 0, 0, 0);
                c = __builtin_amdgcn_mfma_f32_16x16x32_bf16(A2[m], B1[n], c, 0, 0, 0);
                c = __builtin_amdgcn_mfma_f32_16x16x32_bf16(A1[m], B2[n], c, 0, 0, 0);
                c = __builtin_amdgcn_mfma_f32_16x16x32_bf16(A2[m], B2[n], c, 0, 0, 0);
                c = __builtin_amdgcn_mfma_f32_16x16x32_bf16(A3[m], B1[n], c, 0, 0, 0);
                c = __builtin_amdgcn_mfma_f32_16x16x32_bf16(A1[m], B3[n], c, 0, 0, 0);
                acc[m][n] = c;
            }
    }

    // epilogue: C/D layout col=lane&15, row=(lane>>4)*4+i  (m89/m91 verified)
    const int rw = lane >> 4;
#pragma unroll
    for (int n = 0; n < 4; ++n) {
        const int col = bn + wc * 64 + n * 16 + cl;
        const float bv = bias[col];
#pragma unroll
        for (int m = 0; m < 4; ++m) {
            const size_t rbase = (size_t)(bm + wr * 64 + m * 16 + rw * 4);
#pragma unroll
            for (int i = 0; i < 4; ++i)
                C[(rbase + i) * ldc + col] = acc[m][n][i] + bv;
        }
    }
}

// ---------------------------------------------------------------------------
// RoPE cos/sin table: SEQ x 32 entries of (cos, sin), computed in fp64 once.
// ---------------------------------------------------------------------------
__global__ void rope_table(float* __restrict__ tab)
{
    const int idx = blockIdx.x * 256 + threadIdx.x;   // 0 .. SEQ*32-1
    const int s = idx >> 5;
    const int i = idx & 31;
    const double inv = pow(10000.0, -(double)(2 * i) / 64.0);
    const double f = (double)s * inv;
    tab[idx * 2 + 0] = (float)cos(f);
    tab[idx * 2 + 1] = (float)sin(f);
}

// ---------------------------------------------------------------------------
// RoPE applied in place on combined q/k thirds.
// ---------------------------------------------------------------------------
__global__ void rope_apply(float* __restrict__ comb, const float* __restrict__ tab)
{
    const int idx = blockIdx.x * 256 + threadIdx.x;
    const int i     = idx & 31;
    const int h     = (idx >> 5) & 15;
    const int row   = (idx >> 9) & (ROWS - 1);
    const int which = idx >> 21;                 // 0 = q third, 1 = k third
    const int s     = row & (SEQ - 1);

    const float c  = tab[(s * 32 + i) * 2 + 0];
    const float sn = tab[(s * 32 + i) * 2 + 1];

    float* base = comb + (size_t)row * THREE_D + which * D_MODEL + h * H_DIM;
    const float t1 = base[i];
    const float t2 = base[i + 32];
    base[i]      = t1 * c - t2 * sn;
    base[i + 32] = t2 * c + t1 * sn;
}

// ---------------------------------------------------------------------------
// Flash-style attention, fp32 vector, exp2-domain softmax, defer-max (THR=8).
// grid = (SEQ/64, BATCH*N_HEADS), 256 threads.
// ---------------------------------------------------------------------------
__global__ __launch_bounds__(256)
void attn_f32(const float* __restrict__ Qg, const float* __restrict__ Kg,
              const float* __restrict__ Vg, float* __restrict__ ctx)
{
    __shared__ __align__(16) float QsT[64][64];   // [d][qi], pre-scaled
    __shared__ __align__(16) float KVs[64][64];   // phase 1: KsT[d][kj]; phase 2: Vs[k][d]
    __shared__ __align__(16) float Ps[64][68];    // [qi][k], padded

    const int bh = blockIdx.y;
    const int b  = bh >> 4;
    const int h  = bh & 15;
    const int q0 = blockIdx.x * 64;
    const size_t rowBase = (size_t)b * SEQ;
    const int hOff = h * H_DIM;

    const int t  = threadIdx.x;
    const int tx = t & 15;
    const int ty = t >> 4;

    // ---- stage Q transposed + pre-scaled: QsT[d][qi]
    {
        const int qi = t & 63;
        const int c0 = t >> 6;
#pragma unroll
        for (int it = 0; it < 4; ++it) {
            const int cc = c0 + it * 4;
            float4 v = *reinterpret_cast<const float4*>(
                &Qg[(rowBase + q0 + qi) * D_MODEL + hOff + cc * 4]);
            QsT[cc * 4 + 0][qi] = v.x * QK_SCALE;
            QsT[cc * 4 + 1][qi] = v.y * QK_SCALE;
            QsT[cc * 4 + 2][qi] = v.z * QK_SCALE;
            QsT[cc * 4 + 3][qi] = v.w * QK_SCALE;
        }
    }

    float m[4], l[4], acc[4][4];
#pragma unroll
    for (int i = 0; i < 4; ++i) {
        m[i] = -1e30f;
        l[i] = 0.f;
#pragma unroll
        for (int j = 0; j < 4; ++j) acc[i][j] = 0.f;
    }

    for (int k0 = 0; k0 < SEQ; k0 += 64) {
        __syncthreads();
        // ---- stage K transposed: KsT[d][kj]
        {
            const int kj = t & 63;
            const int c0 = t >> 6;
#pragma unroll
            for (int it = 0; it < 4; ++it) {
                const int cc = c0 + it * 4;
                float4 v = *reinterpret_cast<const float4*>(
                    &Kg[(rowBase + k0 + kj) * D_MODEL + hOff + cc * 4]);
                KVs[cc * 4 + 0][kj] = v.x;
                KVs[cc * 4 + 1][kj] = v.y;
                KVs[cc * 4 + 2][kj] = v.z;
                KVs[cc * 4 + 3][kj] = v.w;
            }
        }
        __syncthreads();

        // ---- scores (already in log2 domain via QK_SCALE)
        float s[4][4];
#pragma unroll
        for (int i = 0; i < 4; ++i)
#pragma unroll
            for (int j = 0; j < 4; ++j) s[i][j] = 0.f;

#pragma unroll 8
        for (int d = 0; d < 64; ++d) {
            float4 qv = *reinterpret_cast<const float4*>(&QsT[d][ty * 4]);
            float4 kv = *reinterpret_cast<const float4*>(&KVs[d][tx * 4]);
            const float qa[4] = {qv.x, qv.y, qv.z, qv.w};
            const float ka[4] = {kv.x, kv.y, kv.z, kv.w};
#pragma unroll
            for (int i = 0; i < 4; ++i)
#pragma unroll
                for (int j = 0; j < 4; ++j)
                    s[i][j] = fmaf(qa[i], ka[j], s[i][j]);
        }

        // ---- online softmax, exp2 domain, defer-max THR=8
#pragma unroll
        for (int i = 0; i < 4; ++i) {
            float tm = fmaxf(fmaxf(s[i][0], s[i][1]), fmaxf(s[i][2], s[i][3]));
            tm = fmaxf(tm, __shfl_xor(tm, 1));
            tm = fmaxf(tm, __shfl_xor(tm, 2));
            tm = fmaxf(tm, __shfl_xor(tm, 4));
            tm = fmaxf(tm, __shfl_xor(tm, 8));

            if (tm > m[i] + 8.0f) {                      // rescale only when needed
                const float sc = __builtin_amdgcn_exp2f(m[i] - tm);
                l[i] *= sc;
#pragma unroll
                for (int j = 0; j < 4; ++j) acc[i][j] *= sc;
                m[i] = tm;
            }

            float rs = 0.f;
#pragma unroll
            for (int j = 0; j < 4; ++j) {
                const float p = __builtin_amdgcn_exp2f(s[i][j] - m[i]);
                s[i][j] = p;
                rs += p;
            }
            rs += __shfl_xor(rs, 1);
            rs += __shfl_xor(rs, 2);
            rs += __shfl_xor(rs, 4);
            rs += __shfl_xor(rs, 8);
            l[i] += rs;

            float4 pv = {s[i][0], s[i][1], s[i][2], s[i][3]};
            *reinterpret_cast<float4*>(&Ps[ty * 4 + i][tx * 4]) = pv;
        }

        __syncthreads();
        // ---- stage V row-major into same buffer: Vs[k][d]
        {
            const int c4 = t & 15;
            const int r0 = t >> 4;
#pragma unroll
            for (int it = 0; it < 4; ++it) {
                const int rr = r0 + it * 16;
                float4 v = *reinterpret_cast<const float4*>(
                    &Vg[(rowBase + k0 + rr) * D_MODEL + hOff + c4 * 4]);
                *reinterpret_cast<float4*>(&KVs[rr][c4 * 4]) = v;
            }
        }
        __syncthreads();

        // ---- PV: float4 reads of Ps over k (contiguous) and V rows
#pragma unroll
        for (int kk = 0; kk < 64; kk += 4) {
            float4 p4[4], v4[4];
#pragma unroll
            for (int i = 0; i < 4; ++i)
                p4[i] = *reinterpret_cast<const float4*>(&Ps[ty * 4 + i][kk]);
#pragma unroll
            for (int r = 0; r < 4; ++r)
                v4[r] = *reinterpret_cast<const float4*>(&KVs[kk + r][tx * 4]);
#pragma unroll
            for (int i = 0; i < 4; ++i) {
                const float* pp = reinterpret_cast<const float*>(&p4[i]);
#pragma unroll
                for (int r = 0; r < 4; ++r) {
                    const float p = pp[r];
                    const float* vv = reinterpret_cast<const float*>(&v4[r]);
                    acc[i][0] = fmaf(p, vv[0], acc[i][0]);
                    acc[i][1] = fmaf(p, vv[1], acc[i][1]);
                    acc[i][2] = fmaf(p, vv[2], acc[i][2]);
                    acc[i][3] = fmaf(p, vv[3], acc[i][3]);
                }
            }
        }
    }

    // ---- epilogue
#pragma unroll
    for (int i = 0; i < 4; ++i) {
        const float inv = 1.f / l[i];
        float4 o;
        o.x = acc[i][0] * inv;
        o.y = acc[i][1] * inv;
        o.z = acc[i][2] * inv;
        o.w = acc[i][3] * inv;
        *reinterpret_cast<float4*>(
            &ctx[(rowBase + q0 + ty * 4 + i) * D_MODEL + hOff + tx * 4]) = o;
    }
}

// ---------------------------------------------------------------------------
extern "C" void kernel_launch(void* const* d_in, const int* in_sizes, int n_in,
                              void* d_out, int out_size, void* d_ws, size_t ws_size,
                              hipStream_t stream)
{
    const float* x    = (const float*)d_in[0];
    const float* Win  = (const float*)d_in[1];   // (3072, 1024)
    const float* bin  = (const float*)d_in[2];   // (3072,)
    const float* Wout = (const float*)d_in[3];   // (1024, 1024)
    const float* bout = (const float*)d_in[4];   // (1024,)
    float* out = (float*)d_out;

    float* combined = (float*)d_ws;                                  // ROWS x 3072
    float* qkv  = combined + (size_t)ROWS * THREE_D;                 // 3 x ROWS x 1024
    float* qbuf = qkv;
    float* kbuf = qkv + (size_t)ROWS * D_MODEL;
    float* vbuf = kbuf + (size_t)ROWS * D_MODEL;
    float* tab  = vbuf + (size_t)ROWS * D_MODEL;                     // SEQ*32*2
    float* ctx  = combined;                                          // reuse

    const dim3 blk(256);

    rope_table<<<dim3(SEQ * 32 / 256), blk, 0, stream>>>(tab);

    // GEMM1: combined = x @ Win^T + bin   (M=4096, N=3072, K=1024)
    gemm_bt_mfma<<<dim3(24, 32), blk, 0, stream>>>(
        x, D_MODEL, Win, D_MODEL, bin, combined, THREE_D, D_MODEL,
        24, (size_t)0, (size_t)0, 0, (size_t)0);

    // RoPE in place on q/k thirds of combined
    rope_apply<<<dim3((2 * ROWS * N_HEADS * 32) / 256), blk, 0, stream>>>(combined, tab);

    // fused q/k/v second projection: seg = blockIdx.x/8 selects the third
    gemm_bt_mfma<<<dim3(24, 32), blk, 0, stream>>>(
        combined, THREE_D, Win, D_MODEL, bin, qkv, D_MODEL, D_MODEL,
        8, (size_t)D_MODEL, (size_t)D_MODEL * D_MODEL, D_MODEL,
        (size_t)ROWS * D_MODEL);

    // attention -> ctx (reuses combined storage)
    attn_f32<<<dim3(SEQ / 64, BATCH * N_HEADS), blk, 0, stream>>>(qbuf, kbuf, vbuf, ctx);

    // GEMM3: out = ctx @ Wout^T + bout
    gemm_bt_mfma<<<dim3(8, 32), blk, 0, stream>>>(
        ctx, D_MODEL, Wout, D_MODEL, bout, out, D_MODEL, D_MODEL,
        8, (size_t)0, (size_t)0, 0, (size_t)0);
}

// Round 4
// 579.899 us; speedup vs baseline: 2.6089x; 1.5583x over previous
//
#include <hip/hip_runtime.h>
#include <math.h>

#define D_MODEL   1024
#define N_HEADS   16
#define H_DIM     64
#define SEQ       2048
#define BATCH     2
#define ROWS      (BATCH * SEQ)        // 4096
#define THREE_D   (3 * D_MODEL)       // 3072

// q pre-scale: 1/sqrt(64) * log2(e)  -> softmax in exp2 domain
#define QK_SCALE  (0.125f * 1.44269504088896340736f)

typedef __attribute__((ext_vector_type(8))) short short8v;   // 8 bf16
typedef __attribute__((ext_vector_type(4))) float f32x4;
typedef __attribute__((ext_vector_type(4))) unsigned int uint4v;
typedef __attribute__((ext_vector_type(2))) unsigned int uint2v;

union Frag { uint4v u; short8v s; };

__device__ __forceinline__ void async_copy16(const float* g, float* l)
{
    __builtin_amdgcn_global_load_lds(
        (const __attribute__((address_space(1))) void*)g,
        (__attribute__((address_space(3))) void*)l,
        16, 0, 0);
}

// split fp32 -> 3 bf16 planes (truncation; residuals <=2^-8, 2^-16)
#define SPL(x, j)                                                          \
    {                                                                      \
        const float x_ = (x);                                              \
        const unsigned u1_ = __float_as_uint(x_);                          \
        const float r1_ = x_ - __uint_as_float(u1_ & 0xFFFF0000u);         \
        const unsigned u2_ = __float_as_uint(r1_);                         \
        const float r2_ = r1_ - __uint_as_float(u2_ & 0xFFFF0000u);        \
        h1[j] = (short)(u1_ >> 16);                                        \
        h2[j] = (short)(u2_ >> 16);                                        \
        h3[j] = (short)(__float_as_uint(r2_) >> 16);                       \
    }

// split 8 floats into 3 packed bf16x8 planes (element j = v[j])
__device__ __forceinline__ void split3x8(const float* v, uint4v& U1, uint4v& U2, uint4v& U3)
{
    unsigned b1[8], b2[8], b3[8];
#pragma unroll
    for (int j = 0; j < 8; ++j) {
        const unsigned u = __float_as_uint(v[j]);
        b1[j] = u;
        const float r  = v[j] - __uint_as_float(u & 0xFFFF0000u);
        const unsigned ur = __float_as_uint(r);
        b2[j] = ur;
        const float r2 = r - __uint_as_float(ur & 0xFFFF0000u);
        b3[j] = __float_as_uint(r2);
    }
    U1 = (uint4v){ (b1[0]>>16)|(b1[1]&0xFFFF0000u), (b1[2]>>16)|(b1[3]&0xFFFF0000u),
                   (b1[4]>>16)|(b1[5]&0xFFFF0000u), (b1[6]>>16)|(b1[7]&0xFFFF0000u) };
    U2 = (uint4v){ (b2[0]>>16)|(b2[1]&0xFFFF0000u), (b2[2]>>16)|(b2[3]&0xFFFF0000u),
                   (b2[4]>>16)|(b2[5]&0xFFFF0000u), (b2[6]>>16)|(b2[7]&0xFFFF0000u) };
    U3 = (uint4v){ (b3[0]>>16)|(b3[1]&0xFFFF0000u), (b3[2]>>16)|(b3[3]&0xFFFF0000u),
                   (b3[4]>>16)|(b3[5]&0xFFFF0000u), (b3[6]>>16)|(b3[7]&0xFFFF0000u) };
}

__device__ __forceinline__ uint2v shfl_u2(uint2v v, int src)
{
    uint2v r;
    r.x = (unsigned)__shfl((int)v.x, src);
    r.y = (unsigned)__shfl((int)v.y, src);
    return r;
}

// ---------------------------------------------------------------------------
// GEMM:  C[M,N] = A[M,K] * B[N,K]^T + bias[N]   via bf16x3-split MFMA.
// (unchanged from R2 — verified)
// ---------------------------------------------------------------------------
__global__ __launch_bounds__(256, 2)
void gemm_bt_mfma(const float* __restrict__ A, int lda,
                  const float* __restrict__ B, int ldb,
                  const float* __restrict__ bias,
                  float* __restrict__ C, int ldc, int K,
                  int nbx, size_t segA, size_t segB, int segBias, size_t segC)
{
    __shared__ __align__(16) float As[2][128 * 32];
    __shared__ __align__(16) float Bs[2][128 * 32];

    const int seg = blockIdx.x / nbx;
    const int bxs = blockIdx.x - seg * nbx;
    const int bm  = blockIdx.y * 128;
    const int bn  = bxs * 128;
    A    += (size_t)seg * segA;
    B    += (size_t)seg * segB;
    bias += seg * segBias;
    C    += (size_t)seg * segC;

    const int t    = threadIdx.x;
    const int wid  = t >> 6;
    const int lane = t & 63;
    const int wr   = wid >> 1;
    const int wc   = wid & 1;
    const int cl   = lane & 15;
    const int kq   = lane >> 4;
    const int lrow = lane >> 3;
    const int gs   = lane & 7;

    auto stage = [&](int buf, int k0) {
        const int gl = gs ^ lrow;
#pragma unroll
        for (int q = 0; q < 4; ++q) {
            const int r0  = (wid * 4 + q) * 8;
            const int row = r0 + lrow;
            async_copy16(A + (size_t)(bm + row) * lda + k0 + (gl << 2),
                         &As[buf][r0 * 32]);
            async_copy16(B + (size_t)(bn + row) * ldb + k0 + (gl << 2),
                         &Bs[buf][r0 * 32]);
        }
    };

    f32x4 acc[4][4];
#pragma unroll
    for (int m = 0; m < 4; ++m)
#pragma unroll
        for (int n = 0; n < 4; ++n) acc[m][n] = (f32x4)(0.f);

    const int NT = K >> 5;
    stage(0, 0);

    for (int it = 0; it < NT; ++it) {
        __syncthreads();
        if (it + 1 < NT)
            stage((it + 1) & 1, (it + 1) << 5);

        const float* as = As[it & 1];
        const float* bs = Bs[it & 1];

        short8v A1[4], A2[4], A3[4], B1[4], B2[4], B3[4];
#pragma unroll
        for (int m = 0; m < 4; ++m) {
            const int r  = wr * 64 + m * 16 + cl;
            const int s1 = (2 * kq) ^ (r & 7);
            const float4 lo = *reinterpret_cast<const float4*>(as + r * 32 + (s1 << 2));
            const float4 hi = *reinterpret_cast<const float4*>(as + r * 32 + ((s1 ^ 1) << 2));
            short8v h1, h2, h3;
            SPL(lo.x, 0) SPL(lo.y, 1) SPL(lo.z, 2) SPL(lo.w, 3)
            SPL(hi.x, 4) SPL(hi.y, 5) SPL(hi.z, 6) SPL(hi.w, 7)
            A1[m] = h1; A2[m] = h2; A3[m] = h3;
        }
#pragma unroll
        for (int n = 0; n < 4; ++n) {
            const int r  = wc * 64 + n * 16 + cl;
            const int s1 = (2 * kq) ^ (r & 7);
            const float4 lo = *reinterpret_cast<const float4*>(bs + r * 32 + (s1 << 2));
            const float4 hi = *reinterpret_cast<const float4*>(bs + r * 32 + ((s1 ^ 1) << 2));
            short8v h1, h2, h3;
            SPL(lo.x, 0) SPL(lo.y, 1) SPL(lo.z, 2) SPL(lo.w, 3)
            SPL(hi.x, 4) SPL(hi.y, 5) SPL(hi.z, 6) SPL(hi.w, 7)
            B1[n] = h1; B2[n] = h2; B3[n] = h3;
        }

#pragma unroll
        for (int m = 0; m < 4; ++m)
#pragma unroll
            for (int n = 0; n < 4; ++n) {
                f32x4 c = acc[m][n];
                c = __builtin_amdgcn_mfma_f32_16x16x32_bf16(A1[m], B1[n], c, 0, 0, 0);
                c = __builtin_amdgcn_mfma_f32_16x16x32_bf16(A2[m], B1[n], c, 0, 0, 0);
                c = __builtin_amdgcn_mfma_f32_16x16x32_bf16(A1[m], B2[n], c, 0, 0, 0);
                c = __builtin_amdgcn_mfma_f32_16x16x32_bf16(A2[m], B2[n], c, 0, 0, 0);
                c = __builtin_amdgcn_mfma_f32_16x16x32_bf16(A3[m], B1[n], c, 0, 0, 0);
                c = __builtin_amdgcn_mfma_f32_16x16x32_bf16(A1[m], B3[n], c, 0, 0, 0);
                acc[m][n] = c;
            }
    }

    const int rw = lane >> 4;
#pragma unroll
    for (int n = 0; n < 4; ++n) {
        const int col = bn + wc * 64 + n * 16 + cl;
        const float bv = bias[col];
#pragma unroll
        for (int m = 0; m < 4; ++m) {
            const size_t rbase = (size_t)(bm + wr * 64 + m * 16 + rw * 4);
#pragma unroll
            for (int i = 0; i < 4; ++i)
                C[(rbase + i) * ldc + col] = acc[m][n][i] + bv;
        }
    }
}

// ---------------------------------------------------------------------------
// RoPE cos/sin table
// ---------------------------------------------------------------------------
__global__ void rope_table(float* __restrict__ tab)
{
    const int idx = blockIdx.x * 256 + threadIdx.x;
    const int s = idx >> 5;
    const int i = idx & 31;
    const double inv = pow(10000.0, -(double)(2 * i) / 64.0);
    const double f = (double)s * inv;
    tab[idx * 2 + 0] = (float)cos(f);
    tab[idx * 2 + 1] = (float)sin(f);
}

__global__ void rope_apply(float* __restrict__ comb, const float* __restrict__ tab)
{
    const int idx = blockIdx.x * 256 + threadIdx.x;
    const int i     = idx & 31;
    const int h     = (idx >> 5) & 15;
    const int row   = (idx >> 9) & (ROWS - 1);
    const int which = idx >> 21;
    const int s     = row & (SEQ - 1);

    const float c  = tab[(s * 32 + i) * 2 + 0];
    const float sn = tab[(s * 32 + i) * 2 + 1];

    float* base = comb + (size_t)row * THREE_D + which * D_MODEL + h * H_DIM;
    const float t1 = base[i];
    const float t2 = base[i + 32];
    base[i]      = t1 * c - t2 * sn;
    base[i + 32] = t2 * c + t1 * sn;
}

// ---------------------------------------------------------------------------
// Flash attention via bf16-split MFMA.
// grid = (SEQ/128, BATCH*N_HEADS), 256 threads = 4 waves x 32 q-rows.
// Swapped QK^T: mfma(A=K, B=Q) -> S^T (q = lane&15).  Q in registers (x3
// planes).  K staged in LDS pre-split x3; V staged transposed, pre-split x2.
// P relayout (D-layout -> A-fragment) via in-register shfl permutation.
// ---------------------------------------------------------------------------
__global__ __launch_bounds__(256)
void attn_mfma(const float* __restrict__ Qg, const float* __restrict__ Kg,
               const float* __restrict__ Vg, float* __restrict__ ctx)
{
    __shared__ __align__(16) short Ks1[64 * 72];
    __shared__ __align__(16) short Ks2[64 * 72];
    __shared__ __align__(16) short Ks3[64 * 72];
    __shared__ __align__(16) short Vt1[64 * 72];
    __shared__ __align__(16) short Vt2[64 * 72];

    const int bh = blockIdx.y;
    const int b  = bh >> 4;
    const int h  = bh & 15;
    const int q0 = blockIdx.x * 128;
    const size_t rowBase = (size_t)b * SEQ;
    const int hOff = h * H_DIM;

    const int t    = threadIdx.x;
    const int w    = t >> 6;
    const int lane = t & 63;
    const int cl   = lane & 15;
    const int g    = lane >> 4;
    const int g2   = g >> 1;                  // ks-half select for P relayout
    const int srcA = cl + 16 * (2 * (g & 1)); // shfl sources for P relayout
    const int srcB = srcA + 16;

    // ---- Q fragments (B-operand), 3 planes, pre-scaled; held all kernel
    Frag qf[2][2][3];   // [qs][d-chunk][plane]
#pragma unroll
    for (int qs = 0; qs < 2; ++qs)
#pragma unroll
        for (int c = 0; c < 2; ++c) {
            const float* qp = Qg + (rowBase + q0 + w * 32 + qs * 16 + cl) * D_MODEL
                              + hOff + c * 32 + g * 8;
            const float4 f0 = *reinterpret_cast<const float4*>(qp);
            const float4 f1 = *reinterpret_cast<const float4*>(qp + 4);
            float v[8] = { f0.x * QK_SCALE, f0.y * QK_SCALE, f0.z * QK_SCALE, f0.w * QK_SCALE,
                           f1.x * QK_SCALE, f1.y * QK_SCALE, f1.z * QK_SCALE, f1.w * QK_SCALE };
            split3x8(v, qf[qs][c][0].u, qf[qs][c][1].u, qf[qs][c][2].u);
        }

    f32x4 acc[2][4];
#pragma unroll
    for (int qs = 0; qs < 2; ++qs)
#pragma unroll
        for (int s = 0; s < 4; ++s) acc[qs][s] = (f32x4)(0.f);
    float m[2] = { -1e30f, -1e30f };
    float l[2] = { 0.f, 0.f };

    for (int k0 = 0; k0 < SEQ; k0 += 64) {
        __syncthreads();   // previous tile's LDS reads complete

        // ---- stage K: [k][d] split x3 planes
        {
            const int krow = t >> 2;
            const int dseg = (t & 3) * 16;
            const float* kp = Kg + (rowBase + k0 + krow) * D_MODEL + hOff + dseg;
            float v[16];
            *reinterpret_cast<float4*>(&v[0])  = reinterpret_cast<const float4*>(kp)[0];
            *reinterpret_cast<float4*>(&v[4])  = reinterpret_cast<const float4*>(kp)[1];
            *reinterpret_cast<float4*>(&v[8])  = reinterpret_cast<const float4*>(kp)[2];
            *reinterpret_cast<float4*>(&v[12]) = reinterpret_cast<const float4*>(kp)[3];
            uint4v a1, a2, a3, b1, b2, b3;
            split3x8(v,     a1, a2, a3);
            split3x8(v + 8, b1, b2, b3);
            const int o = krow * 72 + dseg;
            *reinterpret_cast<uint4v*>(&Ks1[o])     = a1;
            *reinterpret_cast<uint4v*>(&Ks1[o + 8]) = b1;
            *reinterpret_cast<uint4v*>(&Ks2[o])     = a2;
            *reinterpret_cast<uint4v*>(&Ks2[o + 8]) = b2;
            *reinterpret_cast<uint4v*>(&Ks3[o])     = a3;
            *reinterpret_cast<uint4v*>(&Ks3[o + 8]) = b3;
        }

        // ---- stage V^T: [d][k] split x2 planes (4x4 register transpose)
        {
            const int kq = t >> 4;          // k = 4*kq + r
            const int dq = t & 15;          // d = 4*dq + rr
            const float* vp = Vg + (rowBase + k0 + kq * 4) * D_MODEL + hOff + dq * 4;
            float va[4][4];
            *reinterpret_cast<float4*>(va[0]) = *reinterpret_cast<const float4*>(vp);
            *reinterpret_cast<float4*>(va[1]) = *reinterpret_cast<const float4*>(vp + D_MODEL);
            *reinterpret_cast<float4*>(va[2]) = *reinterpret_cast<const float4*>(vp + 2 * D_MODEL);
            *reinterpret_cast<float4*>(va[3]) = *reinterpret_cast<const float4*>(vp + 3 * D_MODEL);
#pragma unroll
            for (int rr = 0; rr < 4; ++rr) {
                unsigned ub[4], rb[4];
#pragma unroll
                for (int r = 0; r < 4; ++r) {
                    const float x = va[r][rr];
                    const unsigned u = __float_as_uint(x);
                    ub[r] = u;
                    const float res = x - __uint_as_float(u & 0xFFFF0000u);
                    rb[r] = __float_as_uint(res);
                }
                uint2v w1, w2;
                w1.x = (ub[0] >> 16) | (ub[1] & 0xFFFF0000u);
                w1.y = (ub[2] >> 16) | (ub[3] & 0xFFFF0000u);
                w2.x = (rb[0] >> 16) | (rb[1] & 0xFFFF0000u);
                w2.y = (rb[2] >> 16) | (rb[3] & 0xFFFF0000u);
                const int o = (4 * dq + rr) * 72 + 4 * kq;
                *reinterpret_cast<uint2v*>(&Vt1[o]) = w1;
                *reinterpret_cast<uint2v*>(&Vt2[o]) = w2;
            }
        }
        __syncthreads();   // staged data visible

        // ---- QK^T (swapped): sacc[qs][ks] = S^T subtile, k=16ks+4g+i, q=16qs+cl
        f32x4 sacc[2][4];
#pragma unroll
        for (int qs = 0; qs < 2; ++qs)
#pragma unroll
            for (int ks = 0; ks < 4; ++ks) sacc[qs][ks] = (f32x4)(0.f);

#pragma unroll
        for (int ks = 0; ks < 4; ++ks)
#pragma unroll
            for (int c = 0; c < 2; ++c) {
                const int ko = (ks * 16 + cl) * 72 + c * 32 + g * 8;
                Frag ka1, ka2, ka3;
                ka1.s = *reinterpret_cast<const short8v*>(&Ks1[ko]);
                ka2.s = *reinterpret_cast<const short8v*>(&Ks2[ko]);
                ka3.s = *reinterpret_cast<const short8v*>(&Ks3[ko]);
#pragma unroll
                for (int qs = 0; qs < 2; ++qs) {
                    f32x4 s = sacc[qs][ks];
                    s = __builtin_amdgcn_mfma_f32_16x16x32_bf16(ka1.s, qf[qs][c][0].s, s, 0, 0, 0);
                    s = __builtin_amdgcn_mfma_f32_16x16x32_bf16(ka2.s, qf[qs][c][0].s, s, 0, 0, 0);
                    s = __builtin_amdgcn_mfma_f32_16x16x32_bf16(ka1.s, qf[qs][c][1].s, s, 0, 0, 0);
                    s = __builtin_amdgcn_mfma_f32_16x16x32_bf16(ka2.s, qf[qs][c][1].s, s, 0, 0, 0);
                    s = __builtin_amdgcn_mfma_f32_16x16x32_bf16(ka3.s, qf[qs][c][0].s, s, 0, 0, 0);
                    s = __builtin_amdgcn_mfma_f32_16x16x32_bf16(ka1.s, qf[qs][c][2].s, s, 0, 0, 0);
                    sacc[qs][ks] = s;
                }
            }

        // ---- online softmax (exp2 domain) + P bf16x2 planes
        uint2v P1[2][4], P2[2][4];
#pragma unroll
        for (int qs = 0; qs < 2; ++qs) {
            float tm = -1e30f;
#pragma unroll
            for (int ks = 0; ks < 4; ++ks)
#pragma unroll
                for (int i = 0; i < 4; ++i) tm = fmaxf(tm, sacc[qs][ks][i]);
            tm = fmaxf(tm, __shfl_xor(tm, 16));
            tm = fmaxf(tm, __shfl_xor(tm, 32));

            const float mn = fmaxf(m[qs], tm);
            const float sc = __builtin_amdgcn_exp2f(m[qs] - mn);
            m[qs] = mn;

            float rs = 0.f;
#pragma unroll
            for (int ks = 0; ks < 4; ++ks) {
                float p[4];
                unsigned ub[4], rb[4];
#pragma unroll
                for (int i = 0; i < 4; ++i) {
                    p[i] = __builtin_amdgcn_exp2f(sacc[qs][ks][i] - mn);
                    rs += p[i];
                    const unsigned u = __float_as_uint(p[i]);
                    ub[i] = u;
                    const float res = p[i] - __uint_as_float(u & 0xFFFF0000u);
                    rb[i] = __float_as_uint(res);
                }
                P1[qs][ks] = (uint2v){ (ub[0] >> 16) | (ub[1] & 0xFFFF0000u),
                                       (ub[2] >> 16) | (ub[3] & 0xFFFF0000u) };
                P2[qs][ks] = (uint2v){ (rb[0] >> 16) | (rb[1] & 0xFFFF0000u),
                                       (rb[2] >> 16) | (rb[3] & 0xFFFF0000u) };
            }
            rs += __shfl_xor(rs, 16);
            rs += __shfl_xor(rs, 32);
            l[qs] = l[qs] * sc + rs;

            // rescale acc (acc rows q = 16qs + 4g + i; sc lives at lane cl=q)
            float scv[4];
#pragma unroll
            for (int i = 0; i < 4; ++i) scv[i] = __shfl(sc, 4 * g + i);
#pragma unroll
            for (int s = 0; s < 4; ++s)
#pragma unroll
                for (int i = 0; i < 4; ++i) acc[qs][s][i] *= scv[i];
        }

        // ---- PV: A = P (relayout via shfl), B = V^T from LDS
#pragma unroll
        for (int c = 0; c < 2; ++c) {
            Frag pa1[2], pa2[2];
#pragma unroll
            for (int qs = 0; qs < 2; ++qs) {
                uint2v a0 = shfl_u2(P1[qs][2 * c],     srcA);
                uint2v a1 = shfl_u2(P1[qs][2 * c + 1], srcA);
                uint2v b0 = shfl_u2(P1[qs][2 * c],     srcB);
                uint2v b1 = shfl_u2(P1[qs][2 * c + 1], srcB);
                uint2v aa = g2 ? a1 : a0;
                uint2v bb = g2 ? b1 : b0;
                pa1[qs].u = (uint4v){ aa.x, aa.y, bb.x, bb.y };

                a0 = shfl_u2(P2[qs][2 * c],     srcA);
                a1 = shfl_u2(P2[qs][2 * c + 1], srcA);
                b0 = shfl_u2(P2[qs][2 * c],     srcB);
                b1 = shfl_u2(P2[qs][2 * c + 1], srcB);
                aa = g2 ? a1 : a0;
                bb = g2 ? b1 : b0;
                pa2[qs].u = (uint4v){ aa.x, aa.y, bb.x, bb.y };
            }
#pragma unroll
            for (int s = 0; s < 4; ++s) {
                const int vo = (s * 16 + cl) * 72 + c * 32 + g * 8;
                Frag vb1, vb2;
                vb1.s = *reinterpret_cast<const short8v*>(&Vt1[vo]);
                vb2.s = *reinterpret_cast<const short8v*>(&Vt2[vo]);
#pragma unroll
                for (int qs = 0; qs < 2; ++qs) {
                    f32x4 a = acc[qs][s];
                    a = __builtin_amdgcn_mfma_f32_16x16x32_bf16(pa1[qs].s, vb1.s, a, 0, 0, 0);
                    a = __builtin_amdgcn_mfma_f32_16x16x32_bf16(pa2[qs].s, vb1.s, a, 0, 0, 0);
                    a = __builtin_amdgcn_mfma_f32_16x16x32_bf16(pa1[qs].s, vb2.s, a, 0, 0, 0);
                    acc[qs][s] = a;
                }
            }
        }
    }

    // ---- epilogue: divide by l (lives at lane cl = q) and store
#pragma unroll
    for (int qs = 0; qs < 2; ++qs) {
        const float inv = 1.f / l[qs];
        float iv[4];
#pragma unroll
        for (int i = 0; i < 4; ++i) iv[i] = __shfl(inv, 4 * g + i);
#pragma unroll
        for (int s = 0; s < 4; ++s)
#pragma unroll
            for (int i = 0; i < 4; ++i)
                ctx[(rowBase + q0 + w * 32 + qs * 16 + 4 * g + i) * D_MODEL
                    + hOff + s * 16 + cl] = acc[qs][s][i] * iv[i];
    }
}

// ---------------------------------------------------------------------------
extern "C" void kernel_launch(void* const* d_in, const int* in_sizes, int n_in,
                              void* d_out, int out_size, void* d_ws, size_t ws_size,
                              hipStream_t stream)
{
    const float* x    = (const float*)d_in[0];
    const float* Win  = (const float*)d_in[1];   // (3072, 1024)
    const float* bin  = (const float*)d_in[2];   // (3072,)
    const float* Wout = (const float*)d_in[3];   // (1024, 1024)
    const float* bout = (const float*)d_in[4];   // (1024,)
    float* out = (float*)d_out;

    float* combined = (float*)d_ws;                                  // ROWS x 3072
    float* qkv  = combined + (size_t)ROWS * THREE_D;                 // 3 x ROWS x 1024
    float* qbuf = qkv;
    float* kbuf = qkv + (size_t)ROWS * D_MODEL;
    float* vbuf = kbuf + (size_t)ROWS * D_MODEL;
    float* tab  = vbuf + (size_t)ROWS * D_MODEL;                     // SEQ*32*2
    float* ctx  = combined;                                          // reuse

    const dim3 blk(256);

    rope_table<<<dim3(SEQ * 32 / 256), blk, 0, stream>>>(tab);

    // GEMM1: combined = x @ Win^T + bin   (M=4096, N=3072, K=1024)
    gemm_bt_mfma<<<dim3(24, 32), blk, 0, stream>>>(
        x, D_MODEL, Win, D_MODEL, bin, combined, THREE_D, D_MODEL,
        24, (size_t)0, (size_t)0, 0, (size_t)0);

    // RoPE in place on q/k thirds of combined
    rope_apply<<<dim3((2 * ROWS * N_HEADS * 32) / 256), blk, 0, stream>>>(combined, tab);

    // fused q/k/v second projection: seg = blockIdx.x/8 selects the third
    gemm_bt_mfma<<<dim3(24, 32), blk, 0, stream>>>(
        combined, THREE_D, Win, D_MODEL, bin, qkv, D_MODEL, D_MODEL,
        8, (size_t)D_MODEL, (size_t)D_MODEL * D_MODEL, D_MODEL,
        (size_t)ROWS * D_MODEL);

    // attention -> ctx (reuses combined storage)
    attn_mfma<<<dim3(SEQ / 128, BATCH * N_HEADS), blk, 0, stream>>>(qbuf, kbuf, vbuf, ctx);

    // GEMM3: out = ctx @ Wout^T + bout
    gemm_bt_mfma<<<dim3(8, 32), blk, 0, stream>>>(
        ctx, D_MODEL, Wout, D_MODEL, bout, out, D_MODEL, D_MODEL,
        8, (size_t)0, (size_t)0, 0, (size_t)0);
}

// Round 5
// 513.560 us; speedup vs baseline: 2.9459x; 1.1292x over previous
//
#include <hip/hip_runtime.h>
#include <math.h>

#define D_MODEL   1024
#define N_HEADS   16
#define H_DIM     64
#define SEQ       2048
#define BATCH     2
#define ROWS      (BATCH * SEQ)        // 4096
#define THREE_D   (3 * D_MODEL)       // 3072

// q pre-scale: 1/sqrt(64) * log2(e)  -> softmax in exp2 domain
#define QK_SCALE  (0.125f * 1.44269504088896340736f)

typedef __attribute__((ext_vector_type(8))) short short8v;   // 8 bf16
typedef __attribute__((ext_vector_type(4))) float f32x4;
typedef __attribute__((ext_vector_type(4))) unsigned int uint4v;
typedef __attribute__((ext_vector_type(2))) unsigned int uint2v;

union Frag { uint4v u; short8v s; };

__device__ __forceinline__ void async_copy16(const float* g, float* l)
{
    __builtin_amdgcn_global_load_lds(
        (const __attribute__((address_space(1))) void*)g,
        (__attribute__((address_space(3))) void*)l,
        16, 0, 0);
}

// split fp32 -> 3 bf16 planes (truncation)
#define SPL(x, j)                                                          \
    {                                                                      \
        const float x_ = (x);                                              \
        const unsigned u1_ = __float_as_uint(x_);                          \
        const float r1_ = x_ - __uint_as_float(u1_ & 0xFFFF0000u);         \
        const unsigned u2_ = __float_as_uint(r1_);                         \
        const float r2_ = r1_ - __uint_as_float(u2_ & 0xFFFF0000u);        \
        h1[j] = (short)(u1_ >> 16);                                        \
        h2[j] = (short)(u2_ >> 16);                                        \
        h3[j] = (short)(__float_as_uint(r2_) >> 16);                       \
    }

// split fp32 -> 2 bf16 planes
#define SPL2(x, j)                                                         \
    {                                                                      \
        const float x_ = (x);                                              \
        const unsigned u1_ = __float_as_uint(x_);                          \
        const float r1_ = x_ - __uint_as_float(u1_ & 0xFFFF0000u);         \
        h1[j] = (short)(u1_ >> 16);                                        \
        h2[j] = (short)(__float_as_uint(r1_) >> 16);                       \
    }

// split 8 floats into 3 packed bf16x8 planes
__device__ __forceinline__ void split3x8(const float* v, uint4v& U1, uint4v& U2, uint4v& U3)
{
    unsigned b1[8], b2[8], b3[8];
#pragma unroll
    for (int j = 0; j < 8; ++j) {
        const unsigned u = __float_as_uint(v[j]);
        b1[j] = u;
        const float r  = v[j] - __uint_as_float(u & 0xFFFF0000u);
        const unsigned ur = __float_as_uint(r);
        b2[j] = ur;
        const float r2 = r - __uint_as_float(ur & 0xFFFF0000u);
        b3[j] = __float_as_uint(r2);
    }
    U1 = (uint4v){ (b1[0]>>16)|(b1[1]&0xFFFF0000u), (b1[2]>>16)|(b1[3]&0xFFFF0000u),
                   (b1[4]>>16)|(b1[5]&0xFFFF0000u), (b1[6]>>16)|(b1[7]&0xFFFF0000u) };
    U2 = (uint4v){ (b2[0]>>16)|(b2[1]&0xFFFF0000u), (b2[2]>>16)|(b2[3]&0xFFFF0000u),
                   (b2[4]>>16)|(b2[5]&0xFFFF0000u), (b2[6]>>16)|(b2[7]&0xFFFF0000u) };
    U3 = (uint4v){ (b3[0]>>16)|(b3[1]&0xFFFF0000u), (b3[2]>>16)|(b3[3]&0xFFFF0000u),
                   (b3[4]>>16)|(b3[5]&0xFFFF0000u), (b3[6]>>16)|(b3[7]&0xFFFF0000u) };
}

// split 8 floats into 2 packed bf16x8 planes
__device__ __forceinline__ void split2x8(const float* v, uint4v& U1, uint4v& U2)
{
    unsigned b1[8], b2[8];
#pragma unroll
    for (int j = 0; j < 8; ++j) {
        const unsigned u = __float_as_uint(v[j]);
        b1[j] = u;
        const float r = v[j] - __uint_as_float(u & 0xFFFF0000u);
        b2[j] = __float_as_uint(r);
    }
    U1 = (uint4v){ (b1[0]>>16)|(b1[1]&0xFFFF0000u), (b1[2]>>16)|(b1[3]&0xFFFF0000u),
                   (b1[4]>>16)|(b1[5]&0xFFFF0000u), (b1[6]>>16)|(b1[7]&0xFFFF0000u) };
    U2 = (uint4v){ (b2[0]>>16)|(b2[1]&0xFFFF0000u), (b2[2]>>16)|(b2[3]&0xFFFF0000u),
                   (b2[4]>>16)|(b2[5]&0xFFFF0000u), (b2[6]>>16)|(b2[7]&0xFFFF0000u) };
}

// ---------------------------------------------------------------------------
// GEMM:  C[M,N] = A[M,K] * B[N,K]^T + bias[N]   via bf16-split MFMA.
// A split x3, B split x2, 5 products (dropped a1*b3 ~ 2^-14 random-walk).
// ---------------------------------------------------------------------------
__global__ __launch_bounds__(256, 2)
void gemm_bt_mfma(const float* __restrict__ A, int lda,
                  const float* __restrict__ B, int ldb,
                  const float* __restrict__ bias,
                  float* __restrict__ C, int ldc, int K,
                  int nbx, size_t segA, size_t segB, int segBias, size_t segC)
{
    __shared__ __align__(16) float As[2][128 * 32];
    __shared__ __align__(16) float Bs[2][128 * 32];

    const int seg = blockIdx.x / nbx;
    const int bxs = blockIdx.x - seg * nbx;
    const int bm  = blockIdx.y * 128;
    const int bn  = bxs * 128;
    A    += (size_t)seg * segA;
    B    += (size_t)seg * segB;
    bias += seg * segBias;
    C    += (size_t)seg * segC;

    const int t    = threadIdx.x;
    const int wid  = t >> 6;
    const int lane = t & 63;
    const int wr   = wid >> 1;
    const int wc   = wid & 1;
    const int cl   = lane & 15;
    const int kq   = lane >> 4;
    const int lrow = lane >> 3;
    const int gs   = lane & 7;

    auto stage = [&](int buf, int k0) {
        const int gl = gs ^ lrow;
#pragma unroll
        for (int q = 0; q < 4; ++q) {
            const int r0  = (wid * 4 + q) * 8;
            const int row = r0 + lrow;
            async_copy16(A + (size_t)(bm + row) * lda + k0 + (gl << 2),
                         &As[buf][r0 * 32]);
            async_copy16(B + (size_t)(bn + row) * ldb + k0 + (gl << 2),
                         &Bs[buf][r0 * 32]);
        }
    };

    f32x4 acc[4][4];
#pragma unroll
    for (int m = 0; m < 4; ++m)
#pragma unroll
        for (int n = 0; n < 4; ++n) acc[m][n] = (f32x4)(0.f);

    const int NT = K >> 5;
    stage(0, 0);

    for (int it = 0; it < NT; ++it) {
        __syncthreads();
        if (it + 1 < NT)
            stage((it + 1) & 1, (it + 1) << 5);

        const float* as = As[it & 1];
        const float* bs = Bs[it & 1];

        short8v A1[4], A2[4], A3[4], B1[4], B2[4];
#pragma unroll
        for (int m = 0; m < 4; ++m) {
            const int r  = wr * 64 + m * 16 + cl;
            const int s1 = (2 * kq) ^ (r & 7);
            const float4 lo = *reinterpret_cast<const float4*>(as + r * 32 + (s1 << 2));
            const float4 hi = *reinterpret_cast<const float4*>(as + r * 32 + ((s1 ^ 1) << 2));
            short8v h1, h2, h3;
            SPL(lo.x, 0) SPL(lo.y, 1) SPL(lo.z, 2) SPL(lo.w, 3)
            SPL(hi.x, 4) SPL(hi.y, 5) SPL(hi.z, 6) SPL(hi.w, 7)
            A1[m] = h1; A2[m] = h2; A3[m] = h3;
        }
#pragma unroll
        for (int n = 0; n < 4; ++n) {
            const int r  = wc * 64 + n * 16 + cl;
            const int s1 = (2 * kq) ^ (r & 7);
            const float4 lo = *reinterpret_cast<const float4*>(bs + r * 32 + (s1 << 2));
            const float4 hi = *reinterpret_cast<const float4*>(bs + r * 32 + ((s1 ^ 1) << 2));
            short8v h1, h2;
            SPL2(lo.x, 0) SPL2(lo.y, 1) SPL2(lo.z, 2) SPL2(lo.w, 3)
            SPL2(hi.x, 4) SPL2(hi.y, 5) SPL2(hi.z, 6) SPL2(hi.w, 7)
            B1[n] = h1; B2[n] = h2;
        }

#pragma unroll
        for (int m = 0; m < 4; ++m)
#pragma unroll
            for (int n = 0; n < 4; ++n) {
                f32x4 c = acc[m][n];
                c = __builtin_amdgcn_mfma_f32_16x16x32_bf16(A1[m], B1[n], c, 0, 0, 0);
                c = __builtin_amdgcn_mfma_f32_16x16x32_bf16(A2[m], B1[n], c, 0, 0, 0);
                c = __builtin_amdgcn_mfma_f32_16x16x32_bf16(A1[m], B2[n], c, 0, 0, 0);
                c = __builtin_amdgcn_mfma_f32_16x16x32_bf16(A2[m], B2[n], c, 0, 0, 0);
                c = __builtin_amdgcn_mfma_f32_16x16x32_bf16(A3[m], B1[n], c, 0, 0, 0);
                acc[m][n] = c;
            }
    }

    const int rw = lane >> 4;
#pragma unroll
    for (int n = 0; n < 4; ++n) {
        const int col = bn + wc * 64 + n * 16 + cl;
        const float bv = bias[col];
#pragma unroll
        for (int m = 0; m < 4; ++m) {
            const size_t rbase = (size_t)(bm + wr * 64 + m * 16 + rw * 4);
#pragma unroll
            for (int i = 0; i < 4; ++i)
                C[(rbase + i) * ldc + col] = acc[m][n][i] + bv;
        }
    }
}

// ---------------------------------------------------------------------------
// RoPE
// ---------------------------------------------------------------------------
__global__ void rope_table(float* __restrict__ tab)
{
    const int idx = blockIdx.x * 256 + threadIdx.x;
    const int s = idx >> 5;
    const int i = idx & 31;
    const double inv = pow(10000.0, -(double)(2 * i) / 64.0);
    const double f = (double)s * inv;
    tab[idx * 2 + 0] = (float)cos(f);
    tab[idx * 2 + 1] = (float)sin(f);
}

__global__ void rope_apply(float* __restrict__ comb, const float* __restrict__ tab)
{
    const int idx = blockIdx.x * 256 + threadIdx.x;
    const int i     = idx & 31;
    const int h     = (idx >> 5) & 15;
    const int row   = (idx >> 9) & (ROWS - 1);
    const int which = idx >> 21;
    const int s     = row & (SEQ - 1);

    const float c  = tab[(s * 32 + i) * 2 + 0];
    const float sn = tab[(s * 32 + i) * 2 + 1];

    float* base = comb + (size_t)row * THREE_D + which * D_MODEL + h * H_DIM;
    const float t1 = base[i];
    const float t2 = base[i + 32];
    base[i]      = t1 * c - t2 * sn;
    base[i + 32] = t2 * c + t1 * sn;
}

// ---------------------------------------------------------------------------
// Flash attention, bf16-split MFMA, kv-split 2x with partial outputs.
// grid = (SEQ/128, BATCH*N_HEADS, 2).  256 threads = 4 waves x 32 q-rows.
// K x2 planes (5-product QK vs q x3), V x2, P x2 via per-wave LDS buffer.
// All LDS tiles use XOR-octet swizzle: phys_octet = logical ^ (row&7).
// Partials: Pacc[pblk][128][64] raw acc, Pml[pblk][128] = (m, l).
// ---------------------------------------------------------------------------
__global__ __launch_bounds__(256)
void attn_mfma(const float* __restrict__ Qg, const float* __restrict__ Kg,
               const float* __restrict__ Vg,
               float* __restrict__ Pacc, float* __restrict__ Pml)
{
    __shared__ __align__(16) short Ks1[64 * 64];
    __shared__ __align__(16) short Ks2[64 * 64];
    __shared__ __align__(16) short Vt1[64 * 64];
    __shared__ __align__(16) short Vt2[64 * 64];
    __shared__ __align__(16) short Ps[4 * 2 * 16 * 64];   // [wave][plane][q16][k64]

    const int bh   = blockIdx.y;
    const int b    = bh >> 4;
    const int h    = bh & 15;
    const int q0   = blockIdx.x * 128;
    const int half = blockIdx.z;
    const size_t rowBase = (size_t)b * SEQ;
    const int hOff = h * H_DIM;

    const int t    = threadIdx.x;
    const int w    = t >> 6;
    const int lane = t & 63;
    const int cl   = lane & 15;
    const int g    = lane >> 4;

    // ---- Q fragments (B-operand), 3 planes, pre-scaled
    Frag qf[2][2][3];   // [qs][c][plane]
#pragma unroll
    for (int qs = 0; qs < 2; ++qs)
#pragma unroll
        for (int c = 0; c < 2; ++c) {
            const float* qp = Qg + (rowBase + q0 + w * 32 + qs * 16 + cl) * D_MODEL
                              + hOff + c * 32 + g * 8;
            const float4 f0 = *reinterpret_cast<const float4*>(qp);
            const float4 f1 = *reinterpret_cast<const float4*>(qp + 4);
            float v[8] = { f0.x * QK_SCALE, f0.y * QK_SCALE, f0.z * QK_SCALE, f0.w * QK_SCALE,
                           f1.x * QK_SCALE, f1.y * QK_SCALE, f1.z * QK_SCALE, f1.w * QK_SCALE };
            split3x8(v, qf[qs][c][0].u, qf[qs][c][1].u, qf[qs][c][2].u);
        }

    f32x4 acc[2][4];
#pragma unroll
    for (int qs = 0; qs < 2; ++qs)
#pragma unroll
        for (int s = 0; s < 4; ++s) acc[qs][s] = (f32x4)(0.f);
    float m[2] = { -1e30f, -1e30f };
    float l[2] = { 0.f, 0.f };

    const int kbase = half * (SEQ / 2);
    for (int kt = 0; kt < SEQ / 2; kt += 64) {
        const int k0 = kbase + kt;
        __syncthreads();   // previous tile LDS reads complete

        // ---- stage K: rows k (64), cols d (64), 2 planes, XOR-octet swizzle
        {
            const int krow = t >> 2;
            const int dob  = (t & 3) * 2;       // logical octet base (0,2,4,6)
            const float* kp = Kg + (rowBase + k0 + krow) * D_MODEL + hOff + dob * 8;
            float v[16];
            *reinterpret_cast<float4*>(&v[0])  = reinterpret_cast<const float4*>(kp)[0];
            *reinterpret_cast<float4*>(&v[4])  = reinterpret_cast<const float4*>(kp)[1];
            *reinterpret_cast<float4*>(&v[8])  = reinterpret_cast<const float4*>(kp)[2];
            *reinterpret_cast<float4*>(&v[12]) = reinterpret_cast<const float4*>(kp)[3];
            uint4v a1, a2, b1, b2;
            split2x8(v,     a1, a2);
            split2x8(v + 8, b1, b2);
            const int r7 = krow & 7;
            short* kb1 = Ks1 + krow * 64;
            short* kb2 = Ks2 + krow * 64;
            *reinterpret_cast<uint4v*>(kb1 + ((dob    ) ^ r7) * 8) = a1;
            *reinterpret_cast<uint4v*>(kb1 + ((dob + 1) ^ r7) * 8) = b1;
            *reinterpret_cast<uint4v*>(kb2 + ((dob    ) ^ r7) * 8) = a2;
            *reinterpret_cast<uint4v*>(kb2 + ((dob + 1) ^ r7) * 8) = b2;
        }

        // ---- stage V^T: rows d (64), cols k (64), 2 planes, 4x4 reg transpose
        {
            const int kq = t >> 4;          // k = 4*kq + r
            const int dq = t & 15;          // d = 4*dq + rr
            const float* vp = Vg + (rowBase + k0 + kq * 4) * D_MODEL + hOff + dq * 4;
            float va[4][4];
            *reinterpret_cast<float4*>(va[0]) = *reinterpret_cast<const float4*>(vp);
            *reinterpret_cast<float4*>(va[1]) = *reinterpret_cast<const float4*>(vp + D_MODEL);
            *reinterpret_cast<float4*>(va[2]) = *reinterpret_cast<const float4*>(vp + 2 * D_MODEL);
            *reinterpret_cast<float4*>(va[3]) = *reinterpret_cast<const float4*>(vp + 3 * D_MODEL);
            const int lo = kq >> 1;         // logical octet of k
            const int hf = (kq & 1) * 4;    // half-octet offset (shorts)
#pragma unroll
            for (int rr = 0; rr < 4; ++rr) {
                const int row = 4 * dq + rr;
                unsigned ub[4], rb[4];
#pragma unroll
                for (int r = 0; r < 4; ++r) {
                    const float x = va[r][rr];
                    const unsigned u = __float_as_uint(x);
                    ub[r] = u;
                    rb[r] = __float_as_uint(x - __uint_as_float(u & 0xFFFF0000u));
                }
                uint2v w1, w2;
                w1.x = (ub[0] >> 16) | (ub[1] & 0xFFFF0000u);
                w1.y = (ub[2] >> 16) | (ub[3] & 0xFFFF0000u);
                w2.x = (rb[0] >> 16) | (rb[1] & 0xFFFF0000u);
                w2.y = (rb[2] >> 16) | (rb[3] & 0xFFFF0000u);
                const int o = row * 64 + (lo ^ (row & 7)) * 8 + hf;
                *reinterpret_cast<uint2v*>(&Vt1[o]) = w1;
                *reinterpret_cast<uint2v*>(&Vt2[o]) = w2;
            }
        }
        __syncthreads();

        // ---- QK^T (swapped): sacc[qs][ks], k = 16ks+4g+i, q = cl
        f32x4 sacc[2][4];
#pragma unroll
        for (int qs = 0; qs < 2; ++qs)
#pragma unroll
            for (int ks = 0; ks < 4; ++ks) sacc[qs][ks] = (f32x4)(0.f);

#pragma unroll
        for (int ks = 0; ks < 4; ++ks)
#pragma unroll
            for (int c = 0; c < 2; ++c) {
                const int row = ks * 16 + cl;
                const int po  = row * 64 + ((4 * c + g) ^ (row & 7)) * 8;
                Frag ka1, ka2;
                ka1.s = *reinterpret_cast<const short8v*>(&Ks1[po]);
                ka2.s = *reinterpret_cast<const short8v*>(&Ks2[po]);
#pragma unroll
                for (int qs = 0; qs < 2; ++qs) {
                    f32x4 s = sacc[qs][ks];
                    s = __builtin_amdgcn_mfma_f32_16x16x32_bf16(ka1.s, qf[qs][c][0].s, s, 0, 0, 0);
                    s = __builtin_amdgcn_mfma_f32_16x16x32_bf16(ka2.s, qf[qs][c][0].s, s, 0, 0, 0);
                    s = __builtin_amdgcn_mfma_f32_16x16x32_bf16(ka1.s, qf[qs][c][1].s, s, 0, 0, 0);
                    s = __builtin_amdgcn_mfma_f32_16x16x32_bf16(ka2.s, qf[qs][c][1].s, s, 0, 0, 0);
                    s = __builtin_amdgcn_mfma_f32_16x16x32_bf16(ka1.s, qf[qs][c][2].s, s, 0, 0, 0);
                    sacc[qs][ks] = s;
                }
            }

        // ---- per-qs: softmax -> P (per-wave LDS, 2 planes) -> PV
        short* pb1 = Ps + ((w * 2 + 0) * 16 + cl) * 64;
        short* pb2 = Ps + ((w * 2 + 1) * 16 + cl) * 64;
        const int r7q = cl & 7;

#pragma unroll
        for (int qs = 0; qs < 2; ++qs) {
            float tm = -1e30f;
#pragma unroll
            for (int ks = 0; ks < 4; ++ks)
#pragma unroll
                for (int i = 0; i < 4; ++i) tm = fmaxf(tm, sacc[qs][ks][i]);
            tm = fmaxf(tm, __shfl_xor(tm, 16));
            tm = fmaxf(tm, __shfl_xor(tm, 32));

            const float mn = fmaxf(m[qs], tm);
            const float sc = __builtin_amdgcn_exp2f(m[qs] - mn);
            m[qs] = mn;

            float rs = 0.f;
            uint2v P1[4], P2[4];
#pragma unroll
            for (int ks = 0; ks < 4; ++ks) {
                float p[4];
                unsigned ub[4], rb[4];
#pragma unroll
                for (int i = 0; i < 4; ++i) {
                    p[i] = __builtin_amdgcn_exp2f(sacc[qs][ks][i] - mn);
                    rs += p[i];
                    const unsigned u = __float_as_uint(p[i]);
                    ub[i] = u;
                    rb[i] = __float_as_uint(p[i] - __uint_as_float(u & 0xFFFF0000u));
                }
                P1[ks] = (uint2v){ (ub[0] >> 16) | (ub[1] & 0xFFFF0000u),
                                   (ub[2] >> 16) | (ub[3] & 0xFFFF0000u) };
                P2[ks] = (uint2v){ (rb[0] >> 16) | (rb[1] & 0xFFFF0000u),
                                   (rb[2] >> 16) | (rb[3] & 0xFFFF0000u) };
            }
            rs += __shfl_xor(rs, 16);
            rs += __shfl_xor(rs, 32);
            l[qs] = l[qs] * sc + rs;

            // rescale acc rows (q = 4g+i; sc lives at lane cl = q)
            float scv[4];
#pragma unroll
            for (int i = 0; i < 4; ++i) scv[i] = __shfl(sc, 4 * g + i);
#pragma unroll
            for (int s = 0; s < 4; ++s)
#pragma unroll
                for (int i = 0; i < 4; ++i) acc[qs][s][i] *= scv[i];

            // write P to per-wave LDS (row q = cl, k = 16ks+4g+i)
#pragma unroll
            for (int ks = 0; ks < 4; ++ks) {
                const int off = ((2 * ks + (g >> 1)) ^ r7q) * 8 + (g & 1) * 4;
                *reinterpret_cast<uint2v*>(pb1 + off) = P1[ks];
                *reinterpret_cast<uint2v*>(pb2 + off) = P2[ks];
            }

            // PV: A = P (A-frag: row q = cl), B = V^T
#pragma unroll
            for (int c = 0; c < 2; ++c) {
                const int po = ((4 * c + g) ^ r7q) * 8;
                Frag pa1, pa2;
                pa1.s = *reinterpret_cast<const short8v*>(pb1 + po);
                pa2.s = *reinterpret_cast<const short8v*>(pb2 + po);
#pragma unroll
                for (int s = 0; s < 4; ++s) {
                    const int row = s * 16 + cl;
                    const int vo  = row * 64 + ((4 * c + g) ^ (row & 7)) * 8;
                    Frag vb1, vb2;
                    vb1.s = *reinterpret_cast<const short8v*>(&Vt1[vo]);
                    vb2.s = *reinterpret_cast<const short8v*>(&Vt2[vo]);
                    f32x4 a = acc[qs][s];
                    a = __builtin_amdgcn_mfma_f32_16x16x32_bf16(pa1.s, vb1.s, a, 0, 0, 0);
                    a = __builtin_amdgcn_mfma_f32_16x16x32_bf16(pa2.s, vb1.s, a, 0, 0, 0);
                    a = __builtin_amdgcn_mfma_f32_16x16x32_bf16(pa1.s, vb2.s, a, 0, 0, 0);
                    acc[qs][s] = a;
                }
            }
        }
    }

    // ---- store partials (raw acc + m,l); combine kernel normalizes
    const int pblk = (half * 32 + bh) * 16 + blockIdx.x;
    float* ab = Pacc + (size_t)pblk * (128 * 64);
#pragma unroll
    for (int qs = 0; qs < 2; ++qs) {
#pragma unroll
        for (int s = 0; s < 4; ++s)
#pragma unroll
            for (int i = 0; i < 4; ++i)
                ab[(w * 32 + qs * 16 + 4 * g + i) * 64 + s * 16 + cl] = acc[qs][s][i];
        if (g == 0) {
            float2 ml; ml.x = m[qs]; ml.y = l[qs];
            reinterpret_cast<float2*>(Pml)[pblk * 128 + w * 32 + qs * 16 + cl] = ml;
        }
    }
}

// ---------------------------------------------------------------------------
// Combine the two kv-half partials and normalize -> ctx.
// ---------------------------------------------------------------------------
__global__ __launch_bounds__(256)
void attn_combine(const float* __restrict__ Pacc, const float* __restrict__ Pml,
                  float* __restrict__ ctx)
{
    const int tid = blockIdx.x * 256 + threadIdx.x;    // 0 .. ROWS*D_MODEL/4-1
    const int col = (tid & 255) * 4;                   // 0..1020
    const int row = tid >> 8;                          // 0..4095
    const int b = row >> 11, s = row & 2047;
    const int h = col >> 6,  d = col & 63;
    const int p0 = (b * 16 + h) * 16 + (s >> 7);
    const int q  = s & 127;

    const float2 mlA = reinterpret_cast<const float2*>(Pml)[p0 * 128 + q];
    const float2 mlB = reinterpret_cast<const float2*>(Pml)[(p0 + 512) * 128 + q];
    const float4 a = *reinterpret_cast<const float4*>(
        Pacc + ((size_t)p0 * 128 + q) * 64 + d);
    const float4 c = *reinterpret_cast<const float4*>(
        Pacc + ((size_t)(p0 + 512) * 128 + q) * 64 + d);

    const float mf = fmaxf(mlA.x, mlB.x);
    const float wa = __builtin_amdgcn_exp2f(mlA.x - mf);
    const float wb = __builtin_amdgcn_exp2f(mlB.x - mf);
    const float inv = 1.f / (wa * mlA.y + wb * mlB.y);

    float4 o;
    o.x = (wa * a.x + wb * c.x) * inv;
    o.y = (wa * a.y + wb * c.y) * inv;
    o.z = (wa * a.z + wb * c.z) * inv;
    o.w = (wa * a.w + wb * c.w) * inv;
    *reinterpret_cast<float4*>(&ctx[(size_t)row * D_MODEL + col]) = o;
}

// ---------------------------------------------------------------------------
extern "C" void kernel_launch(void* const* d_in, const int* in_sizes, int n_in,
                              void* d_out, int out_size, void* d_ws, size_t ws_size,
                              hipStream_t stream)
{
    const float* x    = (const float*)d_in[0];
    const float* Win  = (const float*)d_in[1];   // (3072, 1024)
    const float* bin  = (const float*)d_in[2];   // (3072,)
    const float* Wout = (const float*)d_in[3];   // (1024, 1024)
    const float* bout = (const float*)d_in[4];   // (1024,)
    float* out = (float*)d_out;

    float* combined = (float*)d_ws;                                  // ROWS x 3072
    float* qkv  = combined + (size_t)ROWS * THREE_D;                 // 3 x ROWS x 1024
    float* qbuf = qkv;
    float* kbuf = qkv + (size_t)ROWS * D_MODEL;
    float* vbuf = kbuf + (size_t)ROWS * D_MODEL;
    float* tab  = vbuf + (size_t)ROWS * D_MODEL;                     // SEQ*32*2
    float* Pml  = tab + (size_t)SEQ * 64;                            // 1024*128*2
    // attn partial acc reuses the tail of `combined` (dead after QKV GEMM):
    float* ctx  = combined;                                          // ROWS x 1024
    float* Pacc = combined + (size_t)ROWS * D_MODEL;                 // 1024*128*64

    const dim3 blk(256);

    rope_table<<<dim3(SEQ * 32 / 256), blk, 0, stream>>>(tab);

    // GEMM1: combined = x @ Win^T + bin
    gemm_bt_mfma<<<dim3(24, 32), blk, 0, stream>>>(
        x, D_MODEL, Win, D_MODEL, bin, combined, THREE_D, D_MODEL,
        24, (size_t)0, (size_t)0, 0, (size_t)0);

    // RoPE in place on q/k thirds of combined
    rope_apply<<<dim3((2 * ROWS * N_HEADS * 32) / 256), blk, 0, stream>>>(combined, tab);

    // fused q/k/v second projection
    gemm_bt_mfma<<<dim3(24, 32), blk, 0, stream>>>(
        combined, THREE_D, Win, D_MODEL, bin, qkv, D_MODEL, D_MODEL,
        8, (size_t)D_MODEL, (size_t)D_MODEL * D_MODEL, D_MODEL,
        (size_t)ROWS * D_MODEL);

    // attention partials (kv-split 2x) then combine -> ctx
    attn_mfma<<<dim3(SEQ / 128, BATCH * N_HEADS, 2), blk, 0, stream>>>(
        qbuf, kbuf, vbuf, Pacc, Pml);
    attn_combine<<<dim3(ROWS * D_MODEL / 4 / 256), blk, 0, stream>>>(Pacc, Pml, ctx);

    // GEMM3: out = ctx @ Wout^T + bout
    gemm_bt_mfma<<<dim3(8, 32), blk, 0, stream>>>(
        ctx, D_MODEL, Wout, D_MODEL, bout, out, D_MODEL, D_MODEL,
        8, (size_t)0, (size_t)0, 0, (size_t)0);
}